// Round 7
// baseline (359.592 us; speedup 1.0000x reference)
//
#include <hip/hip_runtime.h>
#include <stdint.h>
#include <math.h>

#define D_MODEL 1024
#define NHEAD   16
#define HDIM    64
#define FFDIM   4096
#define SEQ     2048
#define BATCH   2
#define NTOK    (BATCH*SEQ)
#define QKVN    (3*D_MODEL)

typedef __bf16 bf16;
typedef __attribute__((ext_vector_type(8))) __bf16 bf16x8;
typedef __attribute__((ext_vector_type(4))) __bf16 bf16x4;
typedef __attribute__((ext_vector_type(4))) float f32x4;

__device__ __forceinline__ void gld_lds16(const void* g, void* l) {
    __builtin_amdgcn_global_load_lds((__attribute__((address_space(1))) void*)g,
                                     (__attribute__((address_space(3))) void*)l,
                                     16, 0, 0);
}

__device__ __forceinline__ float fast_exp2(float x) {
#if __has_builtin(__builtin_amdgcn_exp2f)
    return __builtin_amdgcn_exp2f(x);
#else
    return __expf(x * 0.69314718056f);
#endif
}

__device__ __forceinline__ float fast_rcp(float x) {
#if __has_builtin(__builtin_amdgcn_rcpf)
    return __builtin_amdgcn_rcpf(x);
#else
    return 1.0f / x;
#endif
}

// tanh-form GELU: max |err vs erf-gelu| ~3e-4, below bf16 output quantization.
__device__ __forceinline__ float gelu_fast(float x) {
    float xx = x * x;
    float y  = x * fmaf(0.035677408137f, xx, 0.7978845608f);
    float z  = fminf(-2.8853900817779268f * y, 126.0f);
    float e  = fast_exp2(z);
    return x * fast_rcp(1.0f + e);
}

#define BARRIER() do {                                         \
    __builtin_amdgcn_s_barrier();                              \
    asm volatile("" ::: "memory");                             \
} while (0)
#define LGKM0() asm volatile("s_waitcnt lgkmcnt(0)" ::: "memory")
#define VMW(N)  asm volatile("s_waitcnt vmcnt(" #N ")" ::: "memory")

// 2-phase boundary for the legacy path
#define PHASE_BAR() do {                                       \
    asm volatile("s_waitcnt vmcnt(0)" ::: "memory");           \
    __builtin_amdgcn_s_barrier();                              \
    asm volatile("" ::: "memory");                             \
} while (0)

// raw barrier that does NOT drain vmcnt (reg-staged pipeline)
#define GEMM_BAR() do {                                        \
    asm volatile("s_waitcnt lgkmcnt(0)" ::: "memory");         \
    __builtin_amdgcn_s_barrier();                              \
    asm volatile("" ::: "memory");                             \
} while (0)

// ---------------- all 4 weight transposes (fp32 W[K][N] -> bf16 Wt[N][K]) ----------------
__global__ __launch_bounds__(256)
void k_transpose_all(const float* __restrict__ w_qkv, const float* __restrict__ w_out,
                     const float* __restrict__ w_fc1, const float* __restrict__ w_fc2,
                     bf16* __restrict__ t_qkv, bf16* __restrict__ t_out,
                     bf16* __restrict__ t_fc1, bf16* __restrict__ t_fc2) {
    __shared__ float tile[32][33];
    int bid = blockIdx.x;
    const float* W; bf16* Wt; int K, N, ti;
    if (bid < 3072)       { W = w_qkv; Wt = t_qkv; K = 1024; N = 3072; ti = bid; }
    else if (bid < 4096)  { W = w_out; Wt = t_out; K = 1024; N = 1024; ti = bid - 3072; }
    else if (bid < 8192)  { W = w_fc1; Wt = t_fc1; K = 1024; N = 4096; ti = bid - 4096; }
    else                  { W = w_fc2; Wt = t_fc2; K = 4096; N = 1024; ti = bid - 8192; }
    int tn = N >> 5;
    int n0 = (ti % tn) * 32, k0 = (ti / tn) * 32;
    int tx = threadIdx.x, ty = threadIdx.y;
#pragma unroll
    for (int i = 0; i < 4; i++)
        tile[ty + i * 8][tx] = W[(size_t)(k0 + ty + i * 8) * N + n0 + tx];
    __syncthreads();
#pragma unroll
    for (int i = 0; i < 4; i++)
        Wt[(size_t)(n0 + ty + i * 8) * K + k0 + tx] = (bf16)tile[tx][ty + i * 8];
}

// ---------------- V transpose + MFMA-k-slot token permutation ----------------
__global__ __launch_bounds__(256)
void k_vtrans(const bf16* __restrict__ qkv, bf16* __restrict__ vT) {
    __shared__ bf16 t[32][33];
    int tok0 = blockIdx.x * 32, f0 = blockIdx.y * 32;
    int tx = threadIdx.x, ty = threadIdx.y;
#pragma unroll
    for (int i = 0; i < 4; i++)
        t[ty + i * 8][tx] = qkv[(size_t)(tok0 + ty + i * 8) * QKVN + 2 * D_MODEL + f0 + tx];
    __syncthreads();
    int s = tx;
    int pp = (s < 16) ? ((s >> 2) * 8 + (s & 3))
                      : (((s - 16) >> 2) * 8 + ((s - 16) & 3) + 4);
#pragma unroll
    for (int i = 0; i < 4; i++)
        vT[(size_t)(f0 + ty + i * 8) * NTOK + tok0 + pp] = t[tx][ty + i * 8];
}

// ---------------- LayerNorm (row = 1024 fp32) -> bf16 ----------------
__global__ __launch_bounds__(256)
void k_layernorm(const float* __restrict__ x, const float* __restrict__ g,
                 const float* __restrict__ b, bf16* __restrict__ out) {
    int row = blockIdx.x;
    int tid = threadIdx.x;
    float4 v = ((const float4*)(x + (size_t)row * D_MODEL))[tid];
    float s  = v.x + v.y + v.z + v.w;
    float ss = v.x * v.x + v.y * v.y + v.z * v.z + v.w * v.w;
#pragma unroll
    for (int off = 32; off > 0; off >>= 1) {
        s  += __shfl_down(s, off, 64);
        ss += __shfl_down(ss, off, 64);
    }
    __shared__ float red[2][4];
    __shared__ float mv[2];
    int wave = tid >> 6, lane = tid & 63;
    if (lane == 0) { red[0][wave] = s; red[1][wave] = ss; }
    __syncthreads();
    if (tid == 0) {
        float S  = red[0][0] + red[0][1] + red[0][2] + red[0][3];
        float SS = red[1][0] + red[1][1] + red[1][2] + red[1][3];
        float mu = S * (1.0f / D_MODEL);
        float var = SS * (1.0f / D_MODEL) - mu * mu;
        mv[0] = mu;
        mv[1] = rsqrtf(var + 1e-5f);
    }
    __syncthreads();
    float mu = mv[0], rs = mv[1];
    float4 gv = ((const float4*)g)[tid];
    float4 bv = ((const float4*)b)[tid];
    bf16x4 ov = { (bf16)((v.x - mu) * rs * gv.x + bv.x),
                  (bf16)((v.y - mu) * rs * gv.y + bv.y),
                  (bf16)((v.z - mu) * rs * gv.z + bv.z),
                  (bf16)((v.w - mu) * rs * gv.w + bv.w) };
    *(bf16x4*)(out + (size_t)row * D_MODEL + tid * 4) = ov;
}

// ---------------- 256x256 8-wave fine-phase MFMA GEMM (m201 schedule) ----------------
// C[M][N] = A[M][K] @ Bt[N][K]^T + bias (+gelu | fp32 atomic).  Grid: (N/256, M/256[, SPLITK]).
// 512 thr = 8 waves (2M x 4N); per-wave out 128x64 = acc[8][4].
// BK=64 as two K-halves; LDS = 2dbuf x 2kh x (A 16KB + B 16KB) = 128 KB (1 blk/CU).
//
// Schedule (per K-tile, 4 phases; each: reads+1 half-tile stage, barrier, lgkm0,
// setprio MFMA16 setprio, barrier; counted vmcnt folded into phases b/d closings):
//   entry invariant: 4 loads in flight = S(t,kh1)
//   a: RD(kh0,rh0) + STAGE A(t+1,kh0) (+2=6)  | bar lgkm0 MFMA bar
//   b: RD(kh0,rh1) + STAGE B(t+1,kh0) (+2=8)  | bar lgkm0 MFMA VMW(4) bar  -> S(t,kh1) landed
//   c: RD(kh1,rh0) + STAGE A(t+1,kh1) (+2=6)  | bar lgkm0 MFMA bar
//   d: RD(kh1,rh1) + STAGE B(t+1,kh1) (+2=8)  | bar lgkm0 MFMA VMW(4) bar  -> S(t+1,kh0) landed
// Reads always target buf, in-flight writes always target buf^1 -> no LDS WAR.
//
// LDS swizzle (proven round 6): phys_col16 = logical_col16 ^ ((row>>1)&3);
// gld_lds writes linearly -> global source col inverse-permuted:
//   src_col16 = (l&3) ^ ((l>>3)&3);  read: xq = 8*(quad ^ ((l16>>1)&3)).
template <int DO_GELU, int ATOMIC, int SPLITK>
__global__ __launch_bounds__(512, 2)
void k_gemm256(const bf16* __restrict__ A, const bf16* __restrict__ Bt,
               const float* __restrict__ bias, bf16* __restrict__ outb,
               float* __restrict__ outf, int M, int N, int K) {
    __shared__ bf16 LA[2][2][8192];   // [dbuf][khalf][256 rows x 32 elems]
    __shared__ bf16 LB[2][2][8192];

    int tid = threadIdx.x;
    int wid = tid >> 6, lane = tid & 63;
    int quad = lane >> 4, l16 = lane & 15;
    int wm = (wid >> 2) * 128;        // wave row offset in tile
    int wn = (wid & 3) * 64;          // wave col offset in tile

    // XCD-aware swizzle (gridDim.x*gridDim.y % 8 == 0 for all users); z untouched
    int nwg = gridDim.x * gridDim.y;
    int bid = blockIdx.y * gridDim.x + blockIdx.x;
    int sid = (bid & 7) * (nwg >> 3) + (bid >> 3);
    int bx = sid % gridDim.x, by = sid / gridDim.x;
    int m0 = by * 256, n0 = bx * 256;

    int Keff = (SPLITK > 1) ? (K / SPLITK) : K;
    int koff = (SPLITK > 1) ? blockIdx.z * Keff : 0;

    // inverse-swizzled global source coords for this lane's staging slot
    int l = lane;
    int rsw = l >> 2;                              // chunk-local row (no row permutation)
    int csw = 8 * ((l & 3) ^ ((l >> 3) & 3));      // source col elems
    const bf16* pA = A  + (size_t)(m0 + 32 * wid + rsw) * K + koff + csw;
    const bf16* pB = Bt + (size_t)(n0 + 32 * wid + rsw) * K + koff + csw;
    int sbase = wid * 1024;           // wave-uniform LDS stage base (HW adds lane*16B)

    // swizzled ds_read column offset (lane-constant)
    int xq = 8 * (quad ^ ((l16 >> 1) & 3));

    f32x4 acc[8][4];
#pragma unroll
    for (int i = 0; i < 8; i++)
#pragma unroll
        for (int j = 0; j < 4; j++) acc[i][j] = (f32x4){0.f, 0.f, 0.f, 0.f};

#define STAGE_A(buf, kh, t) do {                                               \
    gld_lds16(pA + (size_t)(t) * 64 + (kh) * 32,              &LA[buf][kh][sbase]);       \
    gld_lds16(pA + (size_t)16 * K + (size_t)(t) * 64 + (kh) * 32, &LA[buf][kh][sbase + 512]); \
} while (0)
#define STAGE_B(buf, kh, t) do {                                               \
    gld_lds16(pB + (size_t)(t) * 64 + (kh) * 32,              &LB[buf][kh][sbase]);       \
    gld_lds16(pB + (size_t)16 * K + (size_t)(t) * 64 + (kh) * 32, &LB[buf][kh][sbase + 512]); \
} while (0)

    bf16x8 af[4], bfr[4];
#define RD_B(buf, kh)  do {                                                    \
    _Pragma("unroll")                                                          \
    for (int fc = 0; fc < 4; fc++)                                             \
        bfr[fc] = *(const bf16x8*)&LB[buf][kh][(wn + fc * 16 + l16) * 32 + xq];\
} while (0)
#define RD_A(buf, kh, rh) do {                                                 \
    _Pragma("unroll")                                                          \
    for (int fr = 0; fr < 4; fr++)                                             \
        af[fr] = *(const bf16x8*)&LA[buf][kh][(wm + (rh) * 64 + fr * 16 + l16) * 32 + xq]; \
} while (0)
#define MFMA16(rh) do {                                                        \
    __builtin_amdgcn_s_setprio(1);                                             \
    _Pragma("unroll")                                                          \
    for (int fr = 0; fr < 4; fr++)                                             \
        _Pragma("unroll")                                                      \
        for (int fc = 0; fc < 4; fc++)                                         \
            acc[(rh) * 4 + fr][fc] =                                           \
                __builtin_amdgcn_mfma_f32_16x16x32_bf16(af[fr], bfr[fc],       \
                                                        acc[(rh) * 4 + fr][fc], 0, 0, 0); \
    __builtin_amdgcn_s_setprio(0);                                             \
} while (0)

    int nt = Keff / 64;
    int buf = 0;
    // prologue: S(0,kh0) then S(0,kh1) (issue order defines vmcnt FIFO)
    STAGE_A(0, 0, 0); STAGE_B(0, 0, 0);
    STAGE_A(0, 1, 0); STAGE_B(0, 1, 0);
    VMW(4); BARRIER();                 // S(0,kh0) landed; S(0,kh1) in flight

    for (int t = 0; t < nt - 1; t++) {
        // phase a
        RD_B(buf, 0); RD_A(buf, 0, 0);
        STAGE_A(buf ^ 1, 0, t + 1);
        BARRIER(); LGKM0();
        MFMA16(0);
        BARRIER();
        // phase b
        RD_A(buf, 0, 1);
        STAGE_B(buf ^ 1, 0, t + 1);
        BARRIER(); LGKM0();
        MFMA16(1);
        VMW(4); BARRIER();             // S(t,kh1) landed; S(t+1,kh0) in flight
        // phase c
        RD_B(buf, 1); RD_A(buf, 1, 0);
        STAGE_A(buf ^ 1, 1, t + 1);
        BARRIER(); LGKM0();
        MFMA16(0);
        BARRIER();
        // phase d
        RD_A(buf, 1, 1);
        STAGE_B(buf ^ 1, 1, t + 1);
        BARRIER(); LGKM0();
        MFMA16(1);
        VMW(4); BARRIER();             // S(t+1,kh0) landed; S(t+1,kh1) in flight
        buf ^= 1;
    }
    // last tile (no staging): entry has S(last,kh1) in flight
    RD_B(buf, 0); RD_A(buf, 0, 0);
    BARRIER(); LGKM0();
    MFMA16(0);
    BARRIER();
    RD_A(buf, 0, 1);
    BARRIER(); LGKM0();
    MFMA16(1);
    VMW(0); BARRIER();                 // S(last,kh1) landed
    RD_B(buf, 1); RD_A(buf, 1, 0);
    BARRIER(); LGKM0();
    MFMA16(0);
    BARRIER();
    RD_A(buf, 1, 1);
    LGKM0();
    MFMA16(1);

#undef STAGE_A
#undef STAGE_B
#undef RD_A
#undef RD_B
#undef MFMA16

#pragma unroll
    for (int fi = 0; fi < 8; fi++) {
        int row = m0 + wm + fi * 16 + quad * 4;
#pragma unroll
        for (int fc = 0; fc < 4; fc++) {
            int col = n0 + wn + fc * 16 + l16;
            if constexpr (ATOMIC) {
                float bb = (SPLITK == 1 || blockIdx.z == 0) ? bias[col] : 0.0f;
#pragma unroll
                for (int r = 0; r < 4; r++)
                    atomicAdd(&outf[(size_t)(row + r) * N + col], acc[fi][fc][r] + bb);
            } else {
                float bb = bias[col];
#pragma unroll
                for (int r = 0; r < 4; r++) {
                    float v = acc[fi][fc][r] + bb;
                    if (DO_GELU) v = gelu_fast(v);
                    outb[(size_t)(row + r) * N + col] = (bf16)v;
                }
            }
        }
    }
}

// ---------------- legacy 128-tile bf16 MFMA GEMM (out-proj only) ----------------
template <int DO_GELU, int DO_RES, int OUT_BF16, int BN>
__global__ __launch_bounds__(256)
void k_gemm(const bf16* __restrict__ A, const bf16* __restrict__ Bt,
            const float* __restrict__ bias, const float* __restrict__ res,
            float* __restrict__ outf, bf16* __restrict__ outb,
            int M, int N, int K) {
    constexpr int WN = BN / 32;
    __shared__ bf16 As[2][128 * 32];
    __shared__ bf16 Bs[2][BN * 32];
    int tid  = threadIdx.x;
    int wave = tid >> 6, lane = tid & 63;
    int quad = lane >> 4, l16 = lane & 15;

    int nwg = gridDim.x * gridDim.y;
    int bid = blockIdx.y * gridDim.x + blockIdx.x;
    int sid = (bid & 7) * (nwg >> 3) + (bid >> 3);
    int bx = sid % gridDim.x, by = sid / gridDim.x;
    int m0 = by * 128, n0 = bx * BN;
    int wm = (wave >> 1) * 64, wn = (wave & 1) * (BN / 2);

    f32x4 acc[4][WN];
#pragma unroll
    for (int i = 0; i < 4; i++)
#pragma unroll
        for (int j = 0; j < WN; j++) acc[i][j] = (f32x4){0.f, 0.f, 0.f, 0.f};

    int lrow = lane >> 2;
    int lcol = (lane & 3) * 8;
    const bf16* gA0 = A + (size_t)(m0 + wave * 32 + lrow) * K + lcol;
    const bf16* gA1 = gA0 + (size_t)16 * K;
    const bf16* gB0;
    const bf16* gB1 = nullptr;
    if constexpr (BN == 128) {
        gB0 = Bt + (size_t)(n0 + wave * 32 + lrow) * K + lcol;
        gB1 = gB0 + (size_t)16 * K;
    } else {
        gB0 = Bt + (size_t)(n0 + wave * 16 + lrow) * K + lcol;
    }

    int wA0 = wave * 1024 + lane * 8;
    int wA1 = wA0 + 512;
    int wB0 = (BN == 128) ? (wave * 1024 + lane * 8) : (wave * 512 + lane * 8);
    int wB1 = wB0 + 512;

    auto issue = [&](bf16x8* r, int k0) {
        r[0] = *(const bf16x8*)(gA0 + k0);
        r[1] = *(const bf16x8*)(gA1 + k0);
        r[2] = *(const bf16x8*)(gB0 + k0);
        if constexpr (BN == 128) r[3] = *(const bf16x8*)(gB1 + k0);
    };
    auto commit = [&](int buf, const bf16x8* r) {
        *(bf16x8*)(&As[buf][wA0]) = r[0];
        *(bf16x8*)(&As[buf][wA1]) = r[1];
        *(bf16x8*)(&Bs[buf][wB0]) = r[2];
        if constexpr (BN == 128) *(bf16x8*)(&Bs[buf][wB1]) = r[3];
    };
    auto compute = [&](const bf16* cA, const bf16* cB) {
        bf16x8 af[4], bfr[WN];
#pragma unroll
        for (int mi = 0; mi < 4; mi++)
            af[mi] = *(const bf16x8*)(cA + (wm + mi * 16 + l16) * 32 + quad * 8);
#pragma unroll
        for (int ni = 0; ni < WN; ni++)
            bfr[ni] = *(const bf16x8*)(cB + (wn + ni * 16 + l16) * 32 + quad * 8);
#pragma unroll
        for (int mi = 0; mi < 4; mi++)
#pragma unroll
            for (int ni = 0; ni < WN; ni++)
                acc[mi][ni] = __builtin_amdgcn_mfma_f32_16x16x32_bf16(af[mi], bfr[ni], acc[mi][ni], 0, 0, 0);
    };

    int niter = K / 32;
    bf16x8 r0[4], r1[4];
    issue(r0, 0);
    commit(0, r0);
    issue(r1, 32);
    GEMM_BAR();
    for (int t = 1; t + 2 < niter; t += 2) {
        issue(r0, (t + 1) * 32);
        compute(&As[0][0], &Bs[0][0]);
        commit(1, r1);
        GEMM_BAR();
        issue(r1, (t + 2) * 32);
        compute(&As[1][0], &Bs[1][0]);
        commit(0, r0);
        GEMM_BAR();
    }
    compute(&As[0][0], &Bs[0][0]);
    commit(1, r1);
    GEMM_BAR();
    compute(&As[1][0], &Bs[1][0]);

#pragma unroll
    for (int mi = 0; mi < 4; mi++) {
        int row = m0 + wm + mi * 16 + quad * 4;
#pragma unroll
        for (int ni = 0; ni < WN; ni++) {
            int col = n0 + wn + ni * 16 + l16;
            float bb = bias[col];
#pragma unroll
            for (int r = 0; r < 4; r++) {
                float v = acc[mi][ni][r] + bb;
                if (DO_GELU) v = gelu_fast(v);
                size_t idx = (size_t)(row + r) * N + col;
                if (DO_RES) v += res[idx];
                if (OUT_BF16) outb[idx] = (bf16)v;
                else          outf[idx] = v;
            }
        }
    }
}

// ---------------- attention: transposed-S flash, fixed-max softmax, 2-phase K/V pipeline ----------------
__global__ __launch_bounds__(256)
void k_attention2(const bf16* __restrict__ qkv, const bf16* __restrict__ vT,
                  bf16* __restrict__ o) {
    __shared__ bf16 Ks[2][2][64][32];
    __shared__ bf16 Vs[2][2][64][32];

    int tid = threadIdx.x, wave = tid >> 6, lane = tid & 63;
    int quad = lane >> 4, l16 = lane & 15;
    int bh = blockIdx.y;
    int b = bh >> 4, h = bh & 15;
    int q0 = blockIdx.x * 64 + wave * 16;

    const bf16* Qb  = qkv + (size_t)b * SEQ * QKVN + h * HDIM;
    const bf16* Kb  = Qb + D_MODEL;
    const bf16* vTb = vT + (size_t)h * HDIM * NTOK + b * SEQ;

    const float QSCALE = 0.125f * 1.44269504089f;
    bf16x8 qf[2];
#pragma unroll
    for (int c = 0; c < 2; c++) {
        bf16x8 qraw = *(const bf16x8*)(Qb + (size_t)(q0 + l16) * QKVN + c * 32 + quad * 8);
#pragma unroll
        for (int i = 0; i < 8; i++) qf[c][i] = (bf16)((float)qraw[i] * QSCALE);
    }

    const bf16* gK0 = Kb + (size_t)(wave * 16 + (lane >> 2)) * QKVN + (lane & 3) * 8;
    const bf16* gK1 = gK0 + 32;
    const bf16* gV0 = vTb + (size_t)(wave * 16 + (lane >> 2)) * NTOK + (lane & 3) * 8;
    const bf16* gV1 = gV0 + 32;

    f32x4 oacc[4];
#pragma unroll
    for (int i = 0; i < 4; i++) oacc[i] = (f32x4){0.f, 0.f, 0.f, 0.f};
    float lsum = 0.f;

    gld_lds16(gK0, &Ks[0][0][wave * 16][0]);
    gld_lds16(gK1, &Ks[0][1][wave * 16][0]);
    gld_lds16(gV0, &Vs[0][0][wave * 16][0]);
    gld_lds16(gV1, &Vs[0][1][wave * 16][0]);
    PHASE_BAR();

    int buf = 0;
    for (int kv0 = 0; kv0 < SEQ; kv0 += 64) {
        if (kv0 + 64 < SEQ) {
            size_t koff = (size_t)(kv0 + 64) * QKVN;
            gld_lds16(gK0 + koff, &Ks[buf ^ 1][0][wave * 16][0]);
            gld_lds16(gK1 + koff, &Ks[buf ^ 1][1][wave * 16][0]);
            gld_lds16(gV0 + kv0 + 64, &Vs[buf ^ 1][0][wave * 16][0]);
            gld_lds16(gV1 + kv0 + 64, &Vs[buf ^ 1][1][wave * 16][0]);
        }

        f32x4 s[4];
#pragma unroll
        for (int t = 0; t < 4; t++) {
            bf16x8 af0 = *(const bf16x8*)(&Ks[buf][0][t * 16 + l16][quad * 8]);
            bf16x8 af1 = *(const bf16x8*)(&Ks[buf][1][t * 16 + l16][quad * 8]);
            f32x4 z = (f32x4){0.f, 0.f, 0.f, 0.f};
            z = __builtin_amdgcn_mfma_f32_16x16x32_bf16(af0, qf[0], z, 0, 0, 0);
            z = __builtin_amdgcn_mfma_f32_16x16x32_bf16(af1, qf[1], z, 0, 0, 0);
            s[t] = z;
        }

        bf16x4 p[4];
#pragma unroll
        for (int t = 0; t < 4; t++)
#pragma unroll
            for (int r = 0; r < 4; r++) {
                float pf = fast_exp2(s[t][r]);
                lsum += pf;
                p[t][r] = (bf16)pf;
            }

#pragma unroll
        for (int tp = 0; tp < 2; tp++) {
            bf16x8 pa = __builtin_shufflevector(p[2 * tp], p[2 * tp + 1], 0, 1, 2, 3, 4, 5, 6, 7);
#pragma unroll
            for (int nt = 0; nt < 4; nt++) {
                bf16x8 vb = *(const bf16x8*)(&Vs[buf][tp][nt * 16 + l16][quad * 8]);
                oacc[nt] = __builtin_amdgcn_mfma_f32_16x16x32_bf16(pa, vb, oacc[nt], 0, 0, 0);
            }
        }

        PHASE_BAR();
        buf ^= 1;
    }

    lsum += __shfl_xor(lsum, 16, 64);
    lsum += __shfl_xor(lsum, 32, 64);
    float invl[4];
#pragma unroll
    for (int r = 0; r < 4; r++)
        invl[r] = 1.0f / __shfl(lsum, quad * 4 + r, 16);

#pragma unroll
    for (int nt = 0; nt < 4; nt++)
#pragma unroll
        for (int r = 0; r < 4; r++)
            o[(size_t)(b * SEQ + q0 + quad * 4 + r) * D_MODEL + h * HDIM + nt * 16 + l16] =
                (bf16)(oacc[nt][r] * invl[r]);
}

// ---------------- launcher ----------------
extern "C" void kernel_launch(void* const* d_in, const int* in_sizes, int n_in,
                              void* d_out, int out_size, void* d_ws, size_t ws_size,
                              hipStream_t stream) {
    const float* x     = (const float*)d_in[0];
    const float* ln1_g = (const float*)d_in[1];
    const float* ln1_b = (const float*)d_in[2];
    const float* w_qkv = (const float*)d_in[3];
    const float* b_qkv = (const float*)d_in[4];
    const float* w_out = (const float*)d_in[5];
    const float* b_out = (const float*)d_in[6];
    const float* ln2_g = (const float*)d_in[7];
    const float* ln2_b = (const float*)d_in[8];
    const float* w_fc1 = (const float*)d_in[9];
    const float* b_fc1 = (const float*)d_in[10];
    const float* w_fc2 = (const float*)d_in[11];
    const float* b_fc2 = (const float*)d_in[12];
    float* out = (float*)d_out;

    uintptr_t ws = (uintptr_t)d_ws;
    bf16* wt_qkv = (bf16*)(ws + 0);                  //  6291456 B
    bf16* wt_out = (bf16*)(ws + 6291456);            //  2097152 B
    bf16* wt_fc1 = (bf16*)(ws + 8388608);            //  8388608 B
    bf16* wt_fc2 = (bf16*)(ws + 16777216);           //  8388608 B
    bf16* hbuf   = (bf16*)(ws + 25165824);           //  8388608 B
    bf16* vT     = hbuf;
    bf16* qkv    = (bf16*)(ws + 33554432);           // 25165824 B
    bf16* attn_o = (bf16*)(ws + 58720256);           //  8388608 B
    bf16* hgelu  = (bf16*)(ws + 33554432);           // 33554432 B (overlays dead qkv+attn_o)

    k_transpose_all<<<12288, dim3(32, 8), 0, stream>>>(w_qkv, w_out, w_fc1, w_fc2,
                                                       wt_qkv, wt_out, wt_fc1, wt_fc2);

    k_layernorm<<<NTOK, 256, 0, stream>>>(x, ln1_g, ln1_b, hbuf);

    // QKV: 256^2 fine-phase kernel, grid 12x16 = 192 blocks
    k_gemm256<0, 0, 1><<<dim3(QKVN / 256, NTOK / 256), 512, 0, stream>>>(
        hbuf, wt_qkv, b_qkv, qkv, nullptr, NTOK, QKVN, D_MODEL);

    k_vtrans<<<dim3(NTOK / 32, D_MODEL / 32), dim3(32, 8), 0, stream>>>(qkv, vT);

    k_attention2<<<dim3(SEQ / 64, BATCH * NHEAD), 256, 0, stream>>>(qkv, vT, attn_o);

    // out-proj: BN=64, reg-staged 2-deep pipeline
    k_gemm<0, 1, 0, 64><<<dim3(D_MODEL / 64, NTOK / 128), 256, 0, stream>>>(
        attn_o, wt_out, b_out, x, out, nullptr, NTOK, D_MODEL, D_MODEL);

    k_layernorm<<<NTOK, 256, 0, stream>>>(out, ln2_g, ln2_b, hbuf);

    // FC1: 256^2 fine-phase kernel + fast GELU, grid 16x16 = 256 blocks
    k_gemm256<1, 0, 1><<<dim3(FFDIM / 256, NTOK / 256), 512, 0, stream>>>(
        hbuf, wt_fc1, b_fc1, hgelu, nullptr, NTOK, FFDIM, D_MODEL);

    // FC2: 256^2 fine-phase kernel, split-K=4 (grid 4x16x4 = 256 blocks, Keff=1024),
    // fp32 atomicAdd into out (already holds out-proj+residual); z==0 adds bias.
    k_gemm256<0, 1, 4><<<dim3(D_MODEL / 256, NTOK / 256, 4), 512, 0, stream>>>(
        hgelu, wt_fc2, b_fc2, nullptr, out, NTOK, D_MODEL, FFDIM);
}

// Round 8
// 346.784 us; speedup vs baseline: 1.0369x; 1.0369x over previous
//
#include <hip/hip_runtime.h>
#include <stdint.h>
#include <math.h>

#define D_MODEL 1024
#define NHEAD   16
#define HDIM    64
#define FFDIM   4096
#define SEQ     2048
#define BATCH   2
#define NTOK    (BATCH*SEQ)
#define QKVN    (3*D_MODEL)

typedef __bf16 bf16;
typedef __attribute__((ext_vector_type(8))) __bf16 bf16x8;
typedef __attribute__((ext_vector_type(4))) __bf16 bf16x4;
typedef __attribute__((ext_vector_type(4))) float f32x4;

__device__ __forceinline__ void gld_lds16(const void* g, void* l) {
    __builtin_amdgcn_global_load_lds((__attribute__((address_space(1))) void*)g,
                                     (__attribute__((address_space(3))) void*)l,
                                     16, 0, 0);
}

__device__ __forceinline__ float fast_exp2(float x) {
#if __has_builtin(__builtin_amdgcn_exp2f)
    return __builtin_amdgcn_exp2f(x);
#else
    return __expf(x * 0.69314718056f);
#endif
}

__device__ __forceinline__ float fast_rcp(float x) {
#if __has_builtin(__builtin_amdgcn_rcpf)
    return __builtin_amdgcn_rcpf(x);
#else
    return 1.0f / x;
#endif
}

// tanh-form GELU: max |err vs erf-gelu| ~3e-4, below bf16 output quantization.
__device__ __forceinline__ float gelu_fast(float x) {
    float xx = x * x;
    float y  = x * fmaf(0.035677408137f, xx, 0.7978845608f);
    float z  = fminf(-2.8853900817779268f * y, 126.0f);
    float e  = fast_exp2(z);
    return x * fast_rcp(1.0f + e);
}

#define BARRIER() do {                                         \
    __builtin_amdgcn_s_barrier();                              \
    asm volatile("" ::: "memory");                             \
} while (0)
#define LGKM0() asm volatile("s_waitcnt lgkmcnt(0)" ::: "memory")
#define VMW(N)  asm volatile("s_waitcnt vmcnt(" #N ")" ::: "memory")

// 2-phase boundary for the attention pipeline
#define PHASE_BAR() do {                                       \
    asm volatile("s_waitcnt vmcnt(0)" ::: "memory");           \
    __builtin_amdgcn_s_barrier();                              \
    asm volatile("" ::: "memory");                             \
} while (0)

// raw barrier that does NOT drain vmcnt (reg-staged pipeline)
#define GEMM_BAR() do {                                        \
    asm volatile("s_waitcnt lgkmcnt(0)" ::: "memory");         \
    __builtin_amdgcn_s_barrier();                              \
    asm volatile("" ::: "memory");                             \
} while (0)

// ---------------- all 4 weight transposes (fp32 W[K][N] -> bf16 Wt[N][K]) ----------------
__global__ __launch_bounds__(256)
void k_transpose_all(const float* __restrict__ w_qkv, const float* __restrict__ w_out,
                     const float* __restrict__ w_fc1, const float* __restrict__ w_fc2,
                     bf16* __restrict__ t_qkv, bf16* __restrict__ t_out,
                     bf16* __restrict__ t_fc1, bf16* __restrict__ t_fc2) {
    __shared__ float tile[32][33];
    int bid = blockIdx.x;
    const float* W; bf16* Wt; int K, N, ti;
    if (bid < 3072)       { W = w_qkv; Wt = t_qkv; K = 1024; N = 3072; ti = bid; }
    else if (bid < 4096)  { W = w_out; Wt = t_out; K = 1024; N = 1024; ti = bid - 3072; }
    else if (bid < 8192)  { W = w_fc1; Wt = t_fc1; K = 1024; N = 4096; ti = bid - 4096; }
    else                  { W = w_fc2; Wt = t_fc2; K = 4096; N = 1024; ti = bid - 8192; }
    int tn = N >> 5;
    int n0 = (ti % tn) * 32, k0 = (ti / tn) * 32;
    int tx = threadIdx.x, ty = threadIdx.y;
#pragma unroll
    for (int i = 0; i < 4; i++)
        tile[ty + i * 8][tx] = W[(size_t)(k0 + ty + i * 8) * N + n0 + tx];
    __syncthreads();
#pragma unroll
    for (int i = 0; i < 4; i++)
        Wt[(size_t)(n0 + ty + i * 8) * K + k0 + tx] = (bf16)tile[tx][ty + i * 8];
}

// ---------------- V transpose + MFMA-k-slot token permutation ----------------
__global__ __launch_bounds__(256)
void k_vtrans(const bf16* __restrict__ qkv, bf16* __restrict__ vT) {
    __shared__ bf16 t[32][33];
    int tok0 = blockIdx.x * 32, f0 = blockIdx.y * 32;
    int tx = threadIdx.x, ty = threadIdx.y;
#pragma unroll
    for (int i = 0; i < 4; i++)
        t[ty + i * 8][tx] = qkv[(size_t)(tok0 + ty + i * 8) * QKVN + 2 * D_MODEL + f0 + tx];
    __syncthreads();
    int s = tx;
    int pp = (s < 16) ? ((s >> 2) * 8 + (s & 3))
                      : (((s - 16) >> 2) * 8 + ((s - 16) & 3) + 4);
#pragma unroll
    for (int i = 0; i < 4; i++)
        vT[(size_t)(f0 + ty + i * 8) * NTOK + tok0 + pp] = t[tx][ty + i * 8];
}

// ---------------- LayerNorm (row = 1024 fp32) -> bf16 ----------------
__global__ __launch_bounds__(256)
void k_layernorm(const float* __restrict__ x, const float* __restrict__ g,
                 const float* __restrict__ b, bf16* __restrict__ out) {
    int row = blockIdx.x;
    int tid = threadIdx.x;
    float4 v = ((const float4*)(x + (size_t)row * D_MODEL))[tid];
    float s  = v.x + v.y + v.z + v.w;
    float ss = v.x * v.x + v.y * v.y + v.z * v.z + v.w * v.w;
#pragma unroll
    for (int off = 32; off > 0; off >>= 1) {
        s  += __shfl_down(s, off, 64);
        ss += __shfl_down(ss, off, 64);
    }
    __shared__ float red[2][4];
    __shared__ float mv[2];
    int wave = tid >> 6, lane = tid & 63;
    if (lane == 0) { red[0][wave] = s; red[1][wave] = ss; }
    __syncthreads();
    if (tid == 0) {
        float S  = red[0][0] + red[0][1] + red[0][2] + red[0][3];
        float SS = red[1][0] + red[1][1] + red[1][2] + red[1][3];
        float mu = S * (1.0f / D_MODEL);
        float var = SS * (1.0f / D_MODEL) - mu * mu;
        mv[0] = mu;
        mv[1] = rsqrtf(var + 1e-5f);
    }
    __syncthreads();
    float mu = mv[0], rs = mv[1];
    float4 gv = ((const float4*)g)[tid];
    float4 bv = ((const float4*)b)[tid];
    bf16x4 ov = { (bf16)((v.x - mu) * rs * gv.x + bv.x),
                  (bf16)((v.y - mu) * rs * gv.y + bv.y),
                  (bf16)((v.z - mu) * rs * gv.z + bv.z),
                  (bf16)((v.w - mu) * rs * gv.w + bv.w) };
    *(bf16x4*)(out + (size_t)row * D_MODEL + tid * 4) = ov;
}

// ---------------- 256x256 8-wave fine-phase MFMA GEMM, depth-3 pipeline ----------------
// C[M][N] = A[M][K] @ Bt[N][K]^T + bias (+gelu), bf16 out.  Grid: (N/256, M/256).
// 512 thr = 8 waves (2M x 4N); per-wave out 128x64 = acc[8][4].
// BK=64 as two K-halves; LDS = 2dbuf x 2kh x (A 16KB + B 16KB) = 128 KB (1 blk/CU).
//
// Depth-3 counted-vmcnt ledger (4 loads per stage-group, FIFO per wave):
//   entry invariant: 8 in flight = [S(t,kh1):4][S(t+1,kh0):4]
//   a: RD(kh0,rh0); STAGE A(t+1,kh1)->buf^1 (10) | bar lgkm0 MFMA bar
//   b: RD(kh0,rh1); STAGE B(t+1,kh1)       (12) | bar lgkm0 MFMA VMW(8) bar -> S(t,kh1) landed
//   c: RD(kh1,rh0); STAGE A(t+2,kh0)->buf  (10) | bar lgkm0 MFMA bar
//        (WAR-safe: all waves' kh0 reads completed before phase-b's closing barrier)
//   d: RD(kh1,rh1); STAGE B(t+2,kh0)       (12) | bar lgkm0 MFMA VMW(8) bar -> S(t+1,kh0) landed
//   t+2 staging clamped to nt-1 at the tail (dummy lands in an unread slot; counts uniform).
//   Final VMW(0) before C-write so no in-flight LDS writes outlive the block.
//
// LDS swizzle (proven r6/r7, bank-conflict-free): phys_col16 = logical_col16 ^ ((row>>1)&3);
// gld_lds writes linearly -> global source col inverse-permuted:
//   src_col16 = (l&3) ^ ((l>>3)&3);  read: xq = 8*(quad ^ ((l16>>1)&3)).
template <int DO_GELU>
__global__ __launch_bounds__(512, 2)
void k_gemm256(const bf16* __restrict__ A, const bf16* __restrict__ Bt,
               const float* __restrict__ bias, bf16* __restrict__ outb,
               int M, int N, int K) {
    __shared__ bf16 LA[2][2][8192];   // [dbuf][khalf][256 rows x 32 elems]
    __shared__ bf16 LB[2][2][8192];

    int tid = threadIdx.x;
    int wid = tid >> 6, lane = tid & 63;
    int quad = lane >> 4, l16 = lane & 15;
    int wm = (wid >> 2) * 128;        // wave row offset in tile
    int wn = (wid & 3) * 64;          // wave col offset in tile

    // XCD-aware swizzle (gridDim.x*gridDim.y % 8 == 0 for all users)
    int nwg = gridDim.x * gridDim.y;
    int bid = blockIdx.y * gridDim.x + blockIdx.x;
    int sid = (bid & 7) * (nwg >> 3) + (bid >> 3);
    int bx = sid % gridDim.x, by = sid / gridDim.x;
    int m0 = by * 256, n0 = bx * 256;

    // inverse-swizzled global source coords for this lane's staging slot
    int l = lane;
    int rsw = l >> 2;                              // chunk-local row (no row permutation)
    int csw = 8 * ((l & 3) ^ ((l >> 3) & 3));      // source col elems
    const bf16* pA = A  + (size_t)(m0 + 32 * wid + rsw) * K + csw;
    const bf16* pB = Bt + (size_t)(n0 + 32 * wid + rsw) * K + csw;
    int sbase = wid * 1024;           // wave-uniform LDS stage base (HW adds lane*16B)

    // swizzled ds_read column offset (lane-constant)
    int xq = 8 * (quad ^ ((l16 >> 1) & 3));

    f32x4 acc[8][4];
#pragma unroll
    for (int i = 0; i < 8; i++)
#pragma unroll
        for (int j = 0; j < 4; j++) acc[i][j] = (f32x4){0.f, 0.f, 0.f, 0.f};

#define STAGE_A(buf, kh, t) do {                                               \
    gld_lds16(pA + (size_t)(t) * 64 + (kh) * 32,              &LA[buf][kh][sbase]);       \
    gld_lds16(pA + (size_t)16 * K + (size_t)(t) * 64 + (kh) * 32, &LA[buf][kh][sbase + 512]); \
} while (0)
#define STAGE_B(buf, kh, t) do {                                               \
    gld_lds16(pB + (size_t)(t) * 64 + (kh) * 32,              &LB[buf][kh][sbase]);       \
    gld_lds16(pB + (size_t)16 * K + (size_t)(t) * 64 + (kh) * 32, &LB[buf][kh][sbase + 512]); \
} while (0)

    bf16x8 af[4], bfr[4];
#define RD_B(buf, kh)  do {                                                    \
    _Pragma("unroll")                                                          \
    for (int fc = 0; fc < 4; fc++)                                             \
        bfr[fc] = *(const bf16x8*)&LB[buf][kh][(wn + fc * 16 + l16) * 32 + xq];\
} while (0)
#define RD_A(buf, kh, rh) do {                                                 \
    _Pragma("unroll")                                                          \
    for (int fr = 0; fr < 4; fr++)                                             \
        af[fr] = *(const bf16x8*)&LA[buf][kh][(wm + (rh) * 64 + fr * 16 + l16) * 32 + xq]; \
} while (0)
#define MFMA16(rh) do {                                                        \
    __builtin_amdgcn_s_setprio(1);                                             \
    _Pragma("unroll")                                                          \
    for (int fr = 0; fr < 4; fr++)                                             \
        _Pragma("unroll")                                                      \
        for (int fc = 0; fc < 4; fc++)                                         \
            acc[(rh) * 4 + fr][fc] =                                           \
                __builtin_amdgcn_mfma_f32_16x16x32_bf16(af[fr], bfr[fc],       \
                                                        acc[(rh) * 4 + fr][fc], 0, 0, 0); \
    __builtin_amdgcn_s_setprio(0);                                             \
} while (0)

    int nt = K / 64;                   // >= 16 for all users
    int buf = 0;
    // prologue: S(0,kh0), S(0,kh1), S(1,kh0) -> 12 in flight
    STAGE_A(0, 0, 0); STAGE_B(0, 0, 0);
    STAGE_A(0, 1, 0); STAGE_B(0, 1, 0);
    STAGE_A(1, 0, 1); STAGE_B(1, 0, 1);
    VMW(8); BARRIER();                 // S(0,kh0) landed; 8 in flight

    for (int t = 0; t < nt - 1; t++) {
        int ts = (t + 2 < nt) ? (t + 2) : (nt - 1);   // clamped tail staging (dummy)
        // phase a
        RD_B(buf, 0); RD_A(buf, 0, 0);
        STAGE_A(buf ^ 1, 1, t + 1);
        BARRIER(); LGKM0();
        MFMA16(0);
        BARRIER();
        // phase b
        RD_A(buf, 0, 1);
        STAGE_B(buf ^ 1, 1, t + 1);
        BARRIER(); LGKM0();
        MFMA16(1);
        VMW(8); BARRIER();             // S(t,kh1) landed
        // phase c
        RD_B(buf, 1); RD_A(buf, 1, 0);
        STAGE_A(buf, 0, ts);           // into current buf's kh0 (reads done at phase-b bar)
        BARRIER(); LGKM0();
        MFMA16(0);
        BARRIER();
        // phase d
        RD_A(buf, 1, 1);
        STAGE_B(buf, 0, ts);
        BARRIER(); LGKM0();
        MFMA16(1);
        VMW(8); BARRIER();             // S(t+1,kh0) landed
        buf ^= 1;
    }
    // tile nt-1 (no real staging): entry 8 = [S(last,kh1):4][dummy:4]
    RD_B(buf, 0); RD_A(buf, 0, 0);
    BARRIER(); LGKM0();
    MFMA16(0);
    BARRIER();
    RD_A(buf, 0, 1);
    BARRIER(); LGKM0();
    MFMA16(1);
    VMW(4); BARRIER();                 // S(last,kh1) landed (4 dummies remain)
    RD_B(buf, 1); RD_A(buf, 1, 0);
    BARRIER(); LGKM0();
    MFMA16(0);
    BARRIER();
    RD_A(buf, 1, 1);
    LGKM0();
    MFMA16(1);
    VMW(0);                            // drain dummy writes before LDS teardown

#undef STAGE_A
#undef STAGE_B
#undef RD_A
#undef RD_B
#undef MFMA16

#pragma unroll
    for (int fi = 0; fi < 8; fi++) {
        int row = m0 + wm + fi * 16 + quad * 4;
#pragma unroll
        for (int fc = 0; fc < 4; fc++) {
            int col = n0 + wn + fc * 16 + l16;
            float bb = bias[col];
#pragma unroll
            for (int r = 0; r < 4; r++) {
                float v = acc[fi][fc][r] + bb;
                if (DO_GELU) v = gelu_fast(v);
                outb[(size_t)(row + r) * N + col] = (bf16)v;
            }
        }
    }
}

// ---------------- legacy 128-tile bf16 MFMA GEMM (reg-staged 2-deep pipeline) ----------------
// SPLITK=2: blockIdx.z halves K; both halves atomicAdd fp32 into outf (which already
// holds the residual); z==0 also adds bias. Linear epilogue only.
template <int DO_GELU, int DO_RES, int OUT_BF16, int BN, int SPLITK>
__global__ __launch_bounds__(256)
void k_gemm(const bf16* __restrict__ A, const bf16* __restrict__ Bt,
            const float* __restrict__ bias, const float* __restrict__ res,
            float* __restrict__ outf, bf16* __restrict__ outb,
            int M, int N, int K) {
    constexpr int WN = BN / 32;
    __shared__ bf16 As[2][128 * 32];
    __shared__ bf16 Bs[2][BN * 32];
    int tid  = threadIdx.x;
    int wave = tid >> 6, lane = tid & 63;
    int quad = lane >> 4, l16 = lane & 15;

    int nwg = gridDim.x * gridDim.y;
    int bid = blockIdx.y * gridDim.x + blockIdx.x;
    int sid = (bid & 7) * (nwg >> 3) + (bid >> 3);
    int bx = sid % gridDim.x, by = sid / gridDim.x;
    int m0 = by * 128, n0 = bx * BN;
    int wm = (wave >> 1) * 64, wn = (wave & 1) * (BN / 2);

    int Keff = (SPLITK == 2) ? (K >> 1) : K;
    int koff = (SPLITK == 2) ? blockIdx.z * Keff : 0;

    f32x4 acc[4][WN];
#pragma unroll
    for (int i = 0; i < 4; i++)
#pragma unroll
        for (int j = 0; j < WN; j++) acc[i][j] = (f32x4){0.f, 0.f, 0.f, 0.f};

    int lrow = lane >> 2;
    int lcol = (lane & 3) * 8;
    const bf16* gA0 = A + (size_t)(m0 + wave * 32 + lrow) * K + koff + lcol;
    const bf16* gA1 = gA0 + (size_t)16 * K;
    const bf16* gB0;
    const bf16* gB1 = nullptr;
    if constexpr (BN == 128) {
        gB0 = Bt + (size_t)(n0 + wave * 32 + lrow) * K + koff + lcol;
        gB1 = gB0 + (size_t)16 * K;
    } else {
        gB0 = Bt + (size_t)(n0 + wave * 16 + lrow) * K + koff + lcol;
    }

    int wA0 = wave * 1024 + lane * 8;
    int wA1 = wA0 + 512;
    int wB0 = (BN == 128) ? (wave * 1024 + lane * 8) : (wave * 512 + lane * 8);
    int wB1 = wB0 + 512;

    auto issue = [&](bf16x8* r, int k0) {
        r[0] = *(const bf16x8*)(gA0 + k0);
        r[1] = *(const bf16x8*)(gA1 + k0);
        r[2] = *(const bf16x8*)(gB0 + k0);
        if constexpr (BN == 128) r[3] = *(const bf16x8*)(gB1 + k0);
    };
    auto commit = [&](int buf, const bf16x8* r) {
        *(bf16x8*)(&As[buf][wA0]) = r[0];
        *(bf16x8*)(&As[buf][wA1]) = r[1];
        *(bf16x8*)(&Bs[buf][wB0]) = r[2];
        if constexpr (BN == 128) *(bf16x8*)(&Bs[buf][wB1]) = r[3];
    };
    auto compute = [&](const bf16* cA, const bf16* cB) {
        bf16x8 af[4], bfr[WN];
#pragma unroll
        for (int mi = 0; mi < 4; mi++)
            af[mi] = *(const bf16x8*)(cA + (wm + mi * 16 + l16) * 32 + quad * 8);
#pragma unroll
        for (int ni = 0; ni < WN; ni++)
            bfr[ni] = *(const bf16x8*)(cB + (wn + ni * 16 + l16) * 32 + quad * 8);
#pragma unroll
        for (int mi = 0; mi < 4; mi++)
#pragma unroll
            for (int ni = 0; ni < WN; ni++)
                acc[mi][ni] = __builtin_amdgcn_mfma_f32_16x16x32_bf16(af[mi], bfr[ni], acc[mi][ni], 0, 0, 0);
    };

    int niter = Keff / 32;
    bf16x8 r0[4], r1[4];
    issue(r0, 0);
    commit(0, r0);
    issue(r1, 32);
    GEMM_BAR();
    for (int t = 1; t + 2 < niter; t += 2) {
        issue(r0, (t + 1) * 32);
        compute(&As[0][0], &Bs[0][0]);
        commit(1, r1);
        GEMM_BAR();
        issue(r1, (t + 2) * 32);
        compute(&As[1][0], &Bs[1][0]);
        commit(0, r0);
        GEMM_BAR();
    }
    compute(&As[0][0], &Bs[0][0]);
    commit(1, r1);
    GEMM_BAR();
    compute(&As[1][0], &Bs[1][0]);

#pragma unroll
    for (int mi = 0; mi < 4; mi++) {
        int row = m0 + wm + mi * 16 + quad * 4;
#pragma unroll
        for (int ni = 0; ni < WN; ni++) {
            int col = n0 + wn + ni * 16 + l16;
            if constexpr (SPLITK == 2) {
                float bb = (blockIdx.z == 0) ? bias[col] : 0.0f;
#pragma unroll
                for (int r = 0; r < 4; r++)
                    atomicAdd(&outf[(size_t)(row + r) * N + col], acc[mi][ni][r] + bb);
                continue;
            }
            float bb = bias[col];
#pragma unroll
            for (int r = 0; r < 4; r++) {
                float v = acc[mi][ni][r] + bb;
                if (DO_GELU) v = gelu_fast(v);
                size_t idx = (size_t)(row + r) * N + col;
                if (DO_RES) v += res[idx];
                if (OUT_BF16) outb[idx] = (bf16)v;
                else          outf[idx] = v;
            }
        }
    }
}

// ---------------- attention: transposed-S flash, fixed-max softmax, 2-phase K/V pipeline ----------------
__global__ __launch_bounds__(256)
void k_attention2(const bf16* __restrict__ qkv, const bf16* __restrict__ vT,
                  bf16* __restrict__ o) {
    __shared__ bf16 Ks[2][2][64][32];
    __shared__ bf16 Vs[2][2][64][32];

    int tid = threadIdx.x, wave = tid >> 6, lane = tid & 63;
    int quad = lane >> 4, l16 = lane & 15;
    int bh = blockIdx.y;
    int b = bh >> 4, h = bh & 15;
    int q0 = blockIdx.x * 64 + wave * 16;

    const bf16* Qb  = qkv + (size_t)b * SEQ * QKVN + h * HDIM;
    const bf16* Kb  = Qb + D_MODEL;
    const bf16* vTb = vT + (size_t)h * HDIM * NTOK + b * SEQ;

    const float QSCALE = 0.125f * 1.44269504089f;
    bf16x8 qf[2];
#pragma unroll
    for (int c = 0; c < 2; c++) {
        bf16x8 qraw = *(const bf16x8*)(Qb + (size_t)(q0 + l16) * QKVN + c * 32 + quad * 8);
#pragma unroll
        for (int i = 0; i < 8; i++) qf[c][i] = (bf16)((float)qraw[i] * QSCALE);
    }

    const bf16* gK0 = Kb + (size_t)(wave * 16 + (lane >> 2)) * QKVN + (lane & 3) * 8;
    const bf16* gK1 = gK0 + 32;
    const bf16* gV0 = vTb + (size_t)(wave * 16 + (lane >> 2)) * NTOK + (lane & 3) * 8;
    const bf16* gV1 = gV0 + 32;

    f32x4 oacc[4];
#pragma unroll
    for (int i = 0; i < 4; i++) oacc[i] = (f32x4){0.f, 0.f, 0.f, 0.f};
    float lsum = 0.f;

    gld_lds16(gK0, &Ks[0][0][wave * 16][0]);
    gld_lds16(gK1, &Ks[0][1][wave * 16][0]);
    gld_lds16(gV0, &Vs[0][0][wave * 16][0]);
    gld_lds16(gV1, &Vs[0][1][wave * 16][0]);
    PHASE_BAR();

    int buf = 0;
    for (int kv0 = 0; kv0 < SEQ; kv0 += 64) {
        if (kv0 + 64 < SEQ) {
            size_t koff = (size_t)(kv0 + 64) * QKVN;
            gld_lds16(gK0 + koff, &Ks[buf ^ 1][0][wave * 16][0]);
            gld_lds16(gK1 + koff, &Ks[buf ^ 1][1][wave * 16][0]);
            gld_lds16(gV0 + kv0 + 64, &Vs[buf ^ 1][0][wave * 16][0]);
            gld_lds16(gV1 + kv0 + 64, &Vs[buf ^ 1][1][wave * 16][0]);
        }

        f32x4 s[4];
#pragma unroll
        for (int t = 0; t < 4; t++) {
            bf16x8 af0 = *(const bf16x8*)(&Ks[buf][0][t * 16 + l16][quad * 8]);
            bf16x8 af1 = *(const bf16x8*)(&Ks[buf][1][t * 16 + l16][quad * 8]);
            f32x4 z = (f32x4){0.f, 0.f, 0.f, 0.f};
            z = __builtin_amdgcn_mfma_f32_16x16x32_bf16(af0, qf[0], z, 0, 0, 0);
            z = __builtin_amdgcn_mfma_f32_16x16x32_bf16(af1, qf[1], z, 0, 0, 0);
            s[t] = z;
        }

        bf16x4 p[4];
#pragma unroll
        for (int t = 0; t < 4; t++)
#pragma unroll
            for (int r = 0; r < 4; r++) {
                float pf = fast_exp2(s[t][r]);
                lsum += pf;
                p[t][r] = (bf16)pf;
            }

#pragma unroll
        for (int tp = 0; tp < 2; tp++) {
            bf16x8 pa = __builtin_shufflevector(p[2 * tp], p[2 * tp + 1], 0, 1, 2, 3, 4, 5, 6, 7);
#pragma unroll
            for (int nt = 0; nt < 4; nt++) {
                bf16x8 vb = *(const bf16x8*)(&Vs[buf][tp][nt * 16 + l16][quad * 8]);
                oacc[nt] = __builtin_amdgcn_mfma_f32_16x16x32_bf16(pa, vb, oacc[nt], 0, 0, 0);
            }
        }

        PHASE_BAR();
        buf ^= 1;
    }

    lsum += __shfl_xor(lsum, 16, 64);
    lsum += __shfl_xor(lsum, 32, 64);
    float invl[4];
#pragma unroll
    for (int r = 0; r < 4; r++)
        invl[r] = 1.0f / __shfl(lsum, quad * 4 + r, 16);

#pragma unroll
    for (int nt = 0; nt < 4; nt++)
#pragma unroll
        for (int r = 0; r < 4; r++)
            o[(size_t)(b * SEQ + q0 + quad * 4 + r) * D_MODEL + h * HDIM + nt * 16 + l16] =
                (bf16)(oacc[nt][r] * invl[r]);
}

// ---------------- launcher ----------------
extern "C" void kernel_launch(void* const* d_in, const int* in_sizes, int n_in,
                              void* d_out, int out_size, void* d_ws, size_t ws_size,
                              hipStream_t stream) {
    const float* x     = (const float*)d_in[0];
    const float* ln1_g = (const float*)d_in[1];
    const float* ln1_b = (const float*)d_in[2];
    const float* w_qkv = (const float*)d_in[3];
    const float* b_qkv = (const float*)d_in[4];
    const float* w_out = (const float*)d_in[5];
    const float* b_out = (const float*)d_in[6];
    const float* ln2_g = (const float*)d_in[7];
    const float* ln2_b = (const float*)d_in[8];
    const float* w_fc1 = (const float*)d_in[9];
    const float* b_fc1 = (const float*)d_in[10];
    const float* w_fc2 = (const float*)d_in[11];
    const float* b_fc2 = (const float*)d_in[12];
    float* out = (float*)d_out;

    uintptr_t ws = (uintptr_t)d_ws;
    bf16* wt_qkv = (bf16*)(ws + 0);                  //  6291456 B
    bf16* wt_out = (bf16*)(ws + 6291456);            //  2097152 B
    bf16* wt_fc1 = (bf16*)(ws + 8388608);            //  8388608 B
    bf16* wt_fc2 = (bf16*)(ws + 16777216);           //  8388608 B
    bf16* hbuf   = (bf16*)(ws + 25165824);           //  8388608 B
    bf16* vT     = hbuf;
    bf16* qkv    = (bf16*)(ws + 33554432);           // 25165824 B
    bf16* attn_o = (bf16*)(ws + 58720256);           //  8388608 B
    bf16* hgelu  = (bf16*)(ws + 33554432);           // 33554432 B (overlays dead qkv+attn_o)

    k_transpose_all<<<12288, dim3(32, 8), 0, stream>>>(w_qkv, w_out, w_fc1, w_fc2,
                                                       wt_qkv, wt_out, wt_fc1, wt_fc2);

    k_layernorm<<<NTOK, 256, 0, stream>>>(x, ln1_g, ln1_b, hbuf);

    // QKV: 256^2 fine-phase depth-3 kernel, grid 12x16 = 192 blocks
    k_gemm256<0><<<dim3(QKVN / 256, NTOK / 256), 512, 0, stream>>>(
        hbuf, wt_qkv, b_qkv, qkv, NTOK, QKVN, D_MODEL);

    k_vtrans<<<dim3(NTOK / 32, D_MODEL / 32), dim3(32, 8), 0, stream>>>(qkv, vT);

    k_attention2<<<dim3(SEQ / 64, BATCH * NHEAD), 256, 0, stream>>>(qkv, vT, attn_o);

    // out-proj: BN=64, reg-staged 2-deep pipeline
    k_gemm<0, 1, 0, 64, 1><<<dim3(D_MODEL / 64, NTOK / 128), 256, 0, stream>>>(
        attn_o, wt_out, b_out, x, out, nullptr, NTOK, D_MODEL, D_MODEL);

    k_layernorm<<<NTOK, 256, 0, stream>>>(out, ln2_g, ln2_b, hbuf);

    // FC1: 256^2 fine-phase depth-3 kernel + fast GELU, grid 16x16 = 256 blocks
    k_gemm256<1><<<dim3(FFDIM / 256, NTOK / 256), 512, 0, stream>>>(
        hbuf, wt_fc1, b_fc1, hgelu, NTOK, FFDIM, D_MODEL);

    // FC2: legacy 128^2, split-K=2, reg-staged 2-deep; both halves atomicAdd into out
    // (r6-proven 65 us configuration)
    k_gemm<0, 0, 0, 128, 2><<<dim3(D_MODEL / 128, NTOK / 128, 2), 256, 0, stream>>>(
        hgelu, wt_fc2, b_fc2, nullptr, out, nullptr, NTOK, D_MODEL, FFDIM);
}

// Round 9
// 346.634 us; speedup vs baseline: 1.0374x; 1.0004x over previous
//
#include <hip/hip_runtime.h>
#include <stdint.h>
#include <math.h>

#define D_MODEL 1024
#define NHEAD   16
#define HDIM    64
#define FFDIM   4096
#define SEQ     2048
#define BATCH   2
#define NTOK    (BATCH*SEQ)
#define QKVN    (3*D_MODEL)

typedef __bf16 bf16;
typedef __attribute__((ext_vector_type(8))) __bf16 bf16x8;
typedef __attribute__((ext_vector_type(4))) __bf16 bf16x4;
typedef __attribute__((ext_vector_type(4))) float f32x4;

__device__ __forceinline__ void gld_lds16(const void* g, void* l) {
    __builtin_amdgcn_global_load_lds((__attribute__((address_space(1))) void*)g,
                                     (__attribute__((address_space(3))) void*)l,
                                     16, 0, 0);
}

__device__ __forceinline__ float fast_exp2(float x) {
#if __has_builtin(__builtin_amdgcn_exp2f)
    return __builtin_amdgcn_exp2f(x);
#else
    return __expf(x * 0.69314718056f);
#endif
}

__device__ __forceinline__ float fast_rcp(float x) {
#if __has_builtin(__builtin_amdgcn_rcpf)
    return __builtin_amdgcn_rcpf(x);
#else
    return 1.0f / x;
#endif
}

// tanh-form GELU: max |err vs erf-gelu| ~3e-4, below bf16 output quantization.
__device__ __forceinline__ float gelu_fast(float x) {
    float xx = x * x;
    float y  = x * fmaf(0.035677408137f, xx, 0.7978845608f);
    float z  = fminf(-2.8853900817779268f * y, 126.0f);
    float e  = fast_exp2(z);
    return x * fast_rcp(1.0f + e);
}

#define BARRIER() do {                                         \
    __builtin_amdgcn_s_barrier();                              \
    asm volatile("" ::: "memory");                             \
} while (0)
#define LGKM0() asm volatile("s_waitcnt lgkmcnt(0)" ::: "memory")
#define VMW(N)  asm volatile("s_waitcnt vmcnt(" #N ")" ::: "memory")

// 2-phase boundary for the attention pipeline
#define PHASE_BAR() do {                                       \
    asm volatile("s_waitcnt vmcnt(0)" ::: "memory");           \
    __builtin_amdgcn_s_barrier();                              \
    asm volatile("" ::: "memory");                             \
} while (0)

// raw barrier that does NOT drain vmcnt (reg-staged pipeline)
#define GEMM_BAR() do {                                        \
    asm volatile("s_waitcnt lgkmcnt(0)" ::: "memory");         \
    __builtin_amdgcn_s_barrier();                              \
    asm volatile("" ::: "memory");                             \
} while (0)

// ---------------- all 4 weight transposes (fp32 W[K][N] -> bf16 Wt[N][K]) ----------------
__global__ __launch_bounds__(256)
void k_transpose_all(const float* __restrict__ w_qkv, const float* __restrict__ w_out,
                     const float* __restrict__ w_fc1, const float* __restrict__ w_fc2,
                     bf16* __restrict__ t_qkv, bf16* __restrict__ t_out,
                     bf16* __restrict__ t_fc1, bf16* __restrict__ t_fc2) {
    __shared__ float tile[32][33];
    int bid = blockIdx.x;
    const float* W; bf16* Wt; int K, N, ti;
    if (bid < 3072)       { W = w_qkv; Wt = t_qkv; K = 1024; N = 3072; ti = bid; }
    else if (bid < 4096)  { W = w_out; Wt = t_out; K = 1024; N = 1024; ti = bid - 3072; }
    else if (bid < 8192)  { W = w_fc1; Wt = t_fc1; K = 1024; N = 4096; ti = bid - 4096; }
    else                  { W = w_fc2; Wt = t_fc2; K = 4096; N = 1024; ti = bid - 8192; }
    int tn = N >> 5;
    int n0 = (ti % tn) * 32, k0 = (ti / tn) * 32;
    int tx = threadIdx.x, ty = threadIdx.y;
#pragma unroll
    for (int i = 0; i < 4; i++)
        tile[ty + i * 8][tx] = W[(size_t)(k0 + ty + i * 8) * N + n0 + tx];
    __syncthreads();
#pragma unroll
    for (int i = 0; i < 4; i++)
        Wt[(size_t)(n0 + ty + i * 8) * K + k0 + tx] = (bf16)tile[tx][ty + i * 8];
}

// ---------------- V transpose + MFMA-k-slot token permutation ----------------
__global__ __launch_bounds__(256)
void k_vtrans(const bf16* __restrict__ qkv, bf16* __restrict__ vT) {
    __shared__ bf16 t[32][33];
    int tok0 = blockIdx.x * 32, f0 = blockIdx.y * 32;
    int tx = threadIdx.x, ty = threadIdx.y;
#pragma unroll
    for (int i = 0; i < 4; i++)
        t[ty + i * 8][tx] = qkv[(size_t)(tok0 + ty + i * 8) * QKVN + 2 * D_MODEL + f0 + tx];
    __syncthreads();
    int s = tx;
    int pp = (s < 16) ? ((s >> 2) * 8 + (s & 3))
                      : (((s - 16) >> 2) * 8 + ((s - 16) & 3) + 4);
#pragma unroll
    for (int i = 0; i < 4; i++)
        vT[(size_t)(f0 + ty + i * 8) * NTOK + tok0 + pp] = t[tx][ty + i * 8];
}

// ---------------- LayerNorm (row = 1024 fp32) -> bf16 ----------------
__global__ __launch_bounds__(256)
void k_layernorm(const float* __restrict__ x, const float* __restrict__ g,
                 const float* __restrict__ b, bf16* __restrict__ out) {
    int row = blockIdx.x;
    int tid = threadIdx.x;
    float4 v = ((const float4*)(x + (size_t)row * D_MODEL))[tid];
    float s  = v.x + v.y + v.z + v.w;
    float ss = v.x * v.x + v.y * v.y + v.z * v.z + v.w * v.w;
#pragma unroll
    for (int off = 32; off > 0; off >>= 1) {
        s  += __shfl_down(s, off, 64);
        ss += __shfl_down(ss, off, 64);
    }
    __shared__ float red[2][4];
    __shared__ float mv[2];
    int wave = tid >> 6, lane = tid & 63;
    if (lane == 0) { red[0][wave] = s; red[1][wave] = ss; }
    __syncthreads();
    if (tid == 0) {
        float S  = red[0][0] + red[0][1] + red[0][2] + red[0][3];
        float SS = red[1][0] + red[1][1] + red[1][2] + red[1][3];
        float mu = S * (1.0f / D_MODEL);
        float var = SS * (1.0f / D_MODEL) - mu * mu;
        mv[0] = mu;
        mv[1] = rsqrtf(var + 1e-5f);
    }
    __syncthreads();
    float mu = mv[0], rs = mv[1];
    float4 gv = ((const float4*)g)[tid];
    float4 bv = ((const float4*)b)[tid];
    bf16x4 ov = { (bf16)((v.x - mu) * rs * gv.x + bv.x),
                  (bf16)((v.y - mu) * rs * gv.y + bv.y),
                  (bf16)((v.z - mu) * rs * gv.z + bv.z),
                  (bf16)((v.w - mu) * rs * gv.w + bv.w) };
    *(bf16x4*)(out + (size_t)row * D_MODEL + tid * 4) = ov;
}

// ---------------- 256x256 8-wave fine-phase MFMA GEMM, depth-3 pipeline (r8-proven) ----------------
template <int DO_GELU>
__global__ __launch_bounds__(512, 2)
void k_gemm256(const bf16* __restrict__ A, const bf16* __restrict__ Bt,
               const float* __restrict__ bias, bf16* __restrict__ outb,
               int M, int N, int K) {
    __shared__ bf16 LA[2][2][8192];   // [dbuf][khalf][256 rows x 32 elems]
    __shared__ bf16 LB[2][2][8192];

    int tid = threadIdx.x;
    int wid = tid >> 6, lane = tid & 63;
    int quad = lane >> 4, l16 = lane & 15;
    int wm = (wid >> 2) * 128;
    int wn = (wid & 3) * 64;

    int nwg = gridDim.x * gridDim.y;
    int bid = blockIdx.y * gridDim.x + blockIdx.x;
    int sid = (bid & 7) * (nwg >> 3) + (bid >> 3);
    int bx = sid % gridDim.x, by = sid / gridDim.x;
    int m0 = by * 256, n0 = bx * 256;

    int l = lane;
    int rsw = l >> 2;
    int csw = 8 * ((l & 3) ^ ((l >> 3) & 3));
    const bf16* pA = A  + (size_t)(m0 + 32 * wid + rsw) * K + csw;
    const bf16* pB = Bt + (size_t)(n0 + 32 * wid + rsw) * K + csw;
    int sbase = wid * 1024;

    int xq = 8 * (quad ^ ((l16 >> 1) & 3));

    f32x4 acc[8][4];
#pragma unroll
    for (int i = 0; i < 8; i++)
#pragma unroll
        for (int j = 0; j < 4; j++) acc[i][j] = (f32x4){0.f, 0.f, 0.f, 0.f};

#define STAGE_A(buf, kh, t) do {                                               \
    gld_lds16(pA + (size_t)(t) * 64 + (kh) * 32,              &LA[buf][kh][sbase]);       \
    gld_lds16(pA + (size_t)16 * K + (size_t)(t) * 64 + (kh) * 32, &LA[buf][kh][sbase + 512]); \
} while (0)
#define STAGE_B(buf, kh, t) do {                                               \
    gld_lds16(pB + (size_t)(t) * 64 + (kh) * 32,              &LB[buf][kh][sbase]);       \
    gld_lds16(pB + (size_t)16 * K + (size_t)(t) * 64 + (kh) * 32, &LB[buf][kh][sbase + 512]); \
} while (0)

    bf16x8 af[4], bfr[4];
#define RD_B(buf, kh)  do {                                                    \
    _Pragma("unroll")                                                          \
    for (int fc = 0; fc < 4; fc++)                                             \
        bfr[fc] = *(const bf16x8*)&LB[buf][kh][(wn + fc * 16 + l16) * 32 + xq];\
} while (0)
#define RD_A(buf, kh, rh) do {                                                 \
    _Pragma("unroll")                                                          \
    for (int fr = 0; fr < 4; fr++)                                             \
        af[fr] = *(const bf16x8*)&LA[buf][kh][(wm + (rh) * 64 + fr * 16 + l16) * 32 + xq]; \
} while (0)
#define MFMA16(rh) do {                                                        \
    __builtin_amdgcn_s_setprio(1);                                             \
    _Pragma("unroll")                                                          \
    for (int fr = 0; fr < 4; fr++)                                             \
        _Pragma("unroll")                                                      \
        for (int fc = 0; fc < 4; fc++)                                         \
            acc[(rh) * 4 + fr][fc] =                                           \
                __builtin_amdgcn_mfma_f32_16x16x32_bf16(af[fr], bfr[fc],       \
                                                        acc[(rh) * 4 + fr][fc], 0, 0, 0); \
    __builtin_amdgcn_s_setprio(0);                                             \
} while (0)

    int nt = K / 64;
    int buf = 0;
    STAGE_A(0, 0, 0); STAGE_B(0, 0, 0);
    STAGE_A(0, 1, 0); STAGE_B(0, 1, 0);
    STAGE_A(1, 0, 1); STAGE_B(1, 0, 1);
    VMW(8); BARRIER();

    for (int t = 0; t < nt - 1; t++) {
        int ts = (t + 2 < nt) ? (t + 2) : (nt - 1);
        RD_B(buf, 0); RD_A(buf, 0, 0);
        STAGE_A(buf ^ 1, 1, t + 1);
        BARRIER(); LGKM0();
        MFMA16(0);
        BARRIER();
        RD_A(buf, 0, 1);
        STAGE_B(buf ^ 1, 1, t + 1);
        BARRIER(); LGKM0();
        MFMA16(1);
        VMW(8); BARRIER();
        RD_B(buf, 1); RD_A(buf, 1, 0);
        STAGE_A(buf, 0, ts);
        BARRIER(); LGKM0();
        MFMA16(0);
        BARRIER();
        RD_A(buf, 1, 1);
        STAGE_B(buf, 0, ts);
        BARRIER(); LGKM0();
        MFMA16(1);
        VMW(8); BARRIER();
        buf ^= 1;
    }
    RD_B(buf, 0); RD_A(buf, 0, 0);
    BARRIER(); LGKM0();
    MFMA16(0);
    BARRIER();
    RD_A(buf, 0, 1);
    BARRIER(); LGKM0();
    MFMA16(1);
    VMW(4); BARRIER();
    RD_B(buf, 1); RD_A(buf, 1, 0);
    BARRIER(); LGKM0();
    MFMA16(0);
    BARRIER();
    RD_A(buf, 1, 1);
    LGKM0();
    MFMA16(1);
    VMW(0);

#undef STAGE_A
#undef STAGE_B
#undef RD_A
#undef RD_B
#undef MFMA16

#pragma unroll
    for (int fi = 0; fi < 8; fi++) {
        int row = m0 + wm + fi * 16 + quad * 4;
#pragma unroll
        for (int fc = 0; fc < 4; fc++) {
            int col = n0 + wn + fc * 16 + l16;
            float bb = bias[col];
#pragma unroll
            for (int r = 0; r < 4; r++) {
                float v = acc[fi][fc][r] + bb;
                if (DO_GELU) v = gelu_fast(v);
                outb[(size_t)(row + r) * N + col] = (bf16)v;
            }
        }
    }
}

// ---------------- 128x128 4-wave fine-phase MFMA GEMM, split-K atomic (FC2) ----------------
// Same schedule/addressing as k_gemm256, restricted to 4 waves (2Mx2N, 64x64/wave).
// LDS = 2dbuf x 2kh x (A 8KB + B 8KB) = 64 KB -> 2 blocks/CU: cross-block waves cover
// the per-phase barrier gaps that 1-block/CU 256^2 cannot.
// Per tile: 2 phases; each { 8 ds_read + stage 1 half-tile(A+B, 4 loads) -> bar ->
// lgkm0 -> 16 MFMA -> vmcnt(4) -> bar }.  Ledger: entry 4 in flight = S(t,kh1);
// phase kh0 stages S(t+1,kh0) (8), VMW(4) drains S(t,kh1); phase kh1 stages
// S(t+1,kh1) (8), VMW(4) drains S(t+1,kh0). WAR-safe: a slot's readers finished
// >=2 barriers before its restage.
template <int SPLITK>
__global__ __launch_bounds__(256, 2)
void k_gemm128fp(const bf16* __restrict__ A, const bf16* __restrict__ Bt,
                 const float* __restrict__ bias, float* __restrict__ outf,
                 int M, int N, int K) {
    __shared__ bf16 LA[2][2][4096];   // [dbuf][kh][128 rows x 32 elems] = 8KB each
    __shared__ bf16 LB[2][2][4096];

    int tid = threadIdx.x;
    int wid = tid >> 6, lane = tid & 63;
    int quad = lane >> 4, l16 = lane & 15;
    int wm = (wid >> 1) * 64;
    int wn = (wid & 1) * 64;

    int nwg = gridDim.x * gridDim.y;
    int bid = blockIdx.y * gridDim.x + blockIdx.x;
    int sid = (bid & 7) * (nwg >> 3) + (bid >> 3);
    int bx = sid % gridDim.x, by = sid / gridDim.x;
    int m0 = by * 128, n0 = bx * 128;

    int Keff = K / SPLITK;
    int koff = blockIdx.z * Keff;

    int l = lane;
    int rsw = l >> 2;
    int csw = 8 * ((l & 3) ^ ((l >> 3) & 3));
    const bf16* pA = A  + (size_t)(m0 + 32 * wid + rsw) * K + koff + csw;
    const bf16* pB = Bt + (size_t)(n0 + 32 * wid + rsw) * K + koff + csw;
    int sbase = wid * 1024;           // 4 waves x 1024 elems = 4096

    int xq = 8 * (quad ^ ((l16 >> 1) & 3));

    f32x4 acc[4][4];
#pragma unroll
    for (int i = 0; i < 4; i++)
#pragma unroll
        for (int j = 0; j < 4; j++) acc[i][j] = (f32x4){0.f, 0.f, 0.f, 0.f};

#define STAGE_A(buf, kh, t) do {                                               \
    gld_lds16(pA + (size_t)(t) * 64 + (kh) * 32,              &LA[buf][kh][sbase]);       \
    gld_lds16(pA + (size_t)16 * K + (size_t)(t) * 64 + (kh) * 32, &LA[buf][kh][sbase + 512]); \
} while (0)
#define STAGE_B(buf, kh, t) do {                                               \
    gld_lds16(pB + (size_t)(t) * 64 + (kh) * 32,              &LB[buf][kh][sbase]);       \
    gld_lds16(pB + (size_t)16 * K + (size_t)(t) * 64 + (kh) * 32, &LB[buf][kh][sbase + 512]); \
} while (0)

    bf16x8 af[4], bfr[4];
#define RD_B(buf, kh)  do {                                                    \
    _Pragma("unroll")                                                          \
    for (int fc = 0; fc < 4; fc++)                                             \
        bfr[fc] = *(const bf16x8*)&LB[buf][kh][(wn + fc * 16 + l16) * 32 + xq];\
} while (0)
#define RD_A(buf, kh) do {                                                     \
    _Pragma("unroll")                                                          \
    for (int fr = 0; fr < 4; fr++)                                             \
        af[fr] = *(const bf16x8*)&LA[buf][kh][(wm + fr * 16 + l16) * 32 + xq]; \
} while (0)
#define MFMA16() do {                                                          \
    __builtin_amdgcn_s_setprio(1);                                             \
    _Pragma("unroll")                                                          \
    for (int fr = 0; fr < 4; fr++)                                             \
        _Pragma("unroll")                                                      \
        for (int fc = 0; fc < 4; fc++)                                         \
            acc[fr][fc] =                                                      \
                __builtin_amdgcn_mfma_f32_16x16x32_bf16(af[fr], bfr[fc],       \
                                                        acc[fr][fc], 0, 0, 0); \
    __builtin_amdgcn_s_setprio(0);                                             \
} while (0)

    int nt = Keff / 64;               // FC2: 2048/64 = 32
    int buf = 0;
    // prologue: S(0,kh0) then S(0,kh1) -> 8 in flight
    STAGE_A(0, 0, 0); STAGE_B(0, 0, 0);
    STAGE_A(0, 1, 0); STAGE_B(0, 1, 0);
    VMW(4); BARRIER();                // S(0,kh0) landed; S(0,kh1) in flight

    for (int t = 0; t < nt - 1; t++) {
        // phase kh0
        RD_B(buf, 0); RD_A(buf, 0);
        STAGE_A(buf ^ 1, 0, t + 1); STAGE_B(buf ^ 1, 0, t + 1);   // +4 = 8
        BARRIER(); LGKM0();
        MFMA16();
        VMW(4); BARRIER();            // S(t,kh1) landed; S(t+1,kh0) in flight
        // phase kh1
        RD_B(buf, 1); RD_A(buf, 1);
        STAGE_A(buf ^ 1, 1, t + 1); STAGE_B(buf ^ 1, 1, t + 1);   // +4 = 8
        BARRIER(); LGKM0();
        MFMA16();
        VMW(4); BARRIER();            // S(t+1,kh0) landed; S(t+1,kh1) in flight
        buf ^= 1;
    }
    // tile nt-1: entry 4 in flight = S(last,kh1)
    RD_B(buf, 0); RD_A(buf, 0);
    BARRIER(); LGKM0();
    MFMA16();
    VMW(0); BARRIER();                // S(last,kh1) landed; nothing in flight
    RD_B(buf, 1); RD_A(buf, 1);
    LGKM0();
    MFMA16();

#undef STAGE_A
#undef STAGE_B
#undef RD_A
#undef RD_B
#undef MFMA16

#pragma unroll
    for (int fr = 0; fr < 4; fr++) {
        int row = m0 + wm + fr * 16 + quad * 4;
#pragma unroll
        for (int fc = 0; fc < 4; fc++) {
            int col = n0 + wn + fc * 16 + l16;
            float bb = (blockIdx.z == 0) ? bias[col] : 0.0f;
#pragma unroll
            for (int r = 0; r < 4; r++)
                atomicAdd(&outf[(size_t)(row + r) * N + col], acc[fr][fc][r] + bb);
        }
    }
}

// ---------------- legacy 128-tile bf16 MFMA GEMM (out-proj only) ----------------
template <int DO_GELU, int DO_RES, int OUT_BF16, int BN>
__global__ __launch_bounds__(256)
void k_gemm(const bf16* __restrict__ A, const bf16* __restrict__ Bt,
            const float* __restrict__ bias, const float* __restrict__ res,
            float* __restrict__ outf, bf16* __restrict__ outb,
            int M, int N, int K) {
    constexpr int WN = BN / 32;
    __shared__ bf16 As[2][128 * 32];
    __shared__ bf16 Bs[2][BN * 32];
    int tid  = threadIdx.x;
    int wave = tid >> 6, lane = tid & 63;
    int quad = lane >> 4, l16 = lane & 15;

    int nwg = gridDim.x * gridDim.y;
    int bid = blockIdx.y * gridDim.x + blockIdx.x;
    int sid = (bid & 7) * (nwg >> 3) + (bid >> 3);
    int bx = sid % gridDim.x, by = sid / gridDim.x;
    int m0 = by * 128, n0 = bx * BN;
    int wm = (wave >> 1) * 64, wn = (wave & 1) * (BN / 2);

    f32x4 acc[4][WN];
#pragma unroll
    for (int i = 0; i < 4; i++)
#pragma unroll
        for (int j = 0; j < WN; j++) acc[i][j] = (f32x4){0.f, 0.f, 0.f, 0.f};

    int lrow = lane >> 2;
    int lcol = (lane & 3) * 8;
    const bf16* gA0 = A + (size_t)(m0 + wave * 32 + lrow) * K + lcol;
    const bf16* gA1 = gA0 + (size_t)16 * K;
    const bf16* gB0;
    const bf16* gB1 = nullptr;
    if constexpr (BN == 128) {
        gB0 = Bt + (size_t)(n0 + wave * 32 + lrow) * K + lcol;
        gB1 = gB0 + (size_t)16 * K;
    } else {
        gB0 = Bt + (size_t)(n0 + wave * 16 + lrow) * K + lcol;
    }

    int wA0 = wave * 1024 + lane * 8;
    int wA1 = wA0 + 512;
    int wB0 = (BN == 128) ? (wave * 1024 + lane * 8) : (wave * 512 + lane * 8);
    int wB1 = wB0 + 512;

    auto issue = [&](bf16x8* r, int k0) {
        r[0] = *(const bf16x8*)(gA0 + k0);
        r[1] = *(const bf16x8*)(gA1 + k0);
        r[2] = *(const bf16x8*)(gB0 + k0);
        if constexpr (BN == 128) r[3] = *(const bf16x8*)(gB1 + k0);
    };
    auto commit = [&](int buf, const bf16x8* r) {
        *(bf16x8*)(&As[buf][wA0]) = r[0];
        *(bf16x8*)(&As[buf][wA1]) = r[1];
        *(bf16x8*)(&Bs[buf][wB0]) = r[2];
        if constexpr (BN == 128) *(bf16x8*)(&Bs[buf][wB1]) = r[3];
    };
    auto compute = [&](const bf16* cA, const bf16* cB) {
        bf16x8 af[4], bfr[WN];
#pragma unroll
        for (int mi = 0; mi < 4; mi++)
            af[mi] = *(const bf16x8*)(cA + (wm + mi * 16 + l16) * 32 + quad * 8);
#pragma unroll
        for (int ni = 0; ni < WN; ni++)
            bfr[ni] = *(const bf16x8*)(cB + (wn + ni * 16 + l16) * 32 + quad * 8);
#pragma unroll
        for (int mi = 0; mi < 4; mi++)
#pragma unroll
            for (int ni = 0; ni < WN; ni++)
                acc[mi][ni] = __builtin_amdgcn_mfma_f32_16x16x32_bf16(af[mi], bfr[ni], acc[mi][ni], 0, 0, 0);
    };

    int niter = K / 32;
    bf16x8 r0[4], r1[4];
    issue(r0, 0);
    commit(0, r0);
    issue(r1, 32);
    GEMM_BAR();
    for (int t = 1; t + 2 < niter; t += 2) {
        issue(r0, (t + 1) * 32);
        compute(&As[0][0], &Bs[0][0]);
        commit(1, r1);
        GEMM_BAR();
        issue(r1, (t + 2) * 32);
        compute(&As[1][0], &Bs[1][0]);
        commit(0, r0);
        GEMM_BAR();
    }
    compute(&As[0][0], &Bs[0][0]);
    commit(1, r1);
    GEMM_BAR();
    compute(&As[1][0], &Bs[1][0]);

#pragma unroll
    for (int mi = 0; mi < 4; mi++) {
        int row = m0 + wm + mi * 16 + quad * 4;
#pragma unroll
        for (int ni = 0; ni < WN; ni++) {
            int col = n0 + wn + ni * 16 + l16;
            float bb = bias[col];
#pragma unroll
            for (int r = 0; r < 4; r++) {
                float v = acc[mi][ni][r] + bb;
                if (DO_GELU) v = gelu_fast(v);
                size_t idx = (size_t)(row + r) * N + col;
                if (DO_RES) v += res[idx];
                if (OUT_BF16) outb[idx] = (bf16)v;
                else          outf[idx] = v;
            }
        }
    }
}

// ---------------- attention: transposed-S flash, fixed-max softmax, 2-phase K/V pipeline ----------------
__global__ __launch_bounds__(256)
void k_attention2(const bf16* __restrict__ qkv, const bf16* __restrict__ vT,
                  bf16* __restrict__ o) {
    __shared__ bf16 Ks[2][2][64][32];
    __shared__ bf16 Vs[2][2][64][32];

    int tid = threadIdx.x, wave = tid >> 6, lane = tid & 63;
    int quad = lane >> 4, l16 = lane & 15;
    int bh = blockIdx.y;
    int b = bh >> 4, h = bh & 15;
    int q0 = blockIdx.x * 64 + wave * 16;

    const bf16* Qb  = qkv + (size_t)b * SEQ * QKVN + h * HDIM;
    const bf16* Kb  = Qb + D_MODEL;
    const bf16* vTb = vT + (size_t)h * HDIM * NTOK + b * SEQ;

    const float QSCALE = 0.125f * 1.44269504089f;
    bf16x8 qf[2];
#pragma unroll
    for (int c = 0; c < 2; c++) {
        bf16x8 qraw = *(const bf16x8*)(Qb + (size_t)(q0 + l16) * QKVN + c * 32 + quad * 8);
#pragma unroll
        for (int i = 0; i < 8; i++) qf[c][i] = (bf16)((float)qraw[i] * QSCALE);
    }

    const bf16* gK0 = Kb + (size_t)(wave * 16 + (lane >> 2)) * QKVN + (lane & 3) * 8;
    const bf16* gK1 = gK0 + 32;
    const bf16* gV0 = vTb + (size_t)(wave * 16 + (lane >> 2)) * NTOK + (lane & 3) * 8;
    const bf16* gV1 = gV0 + 32;

    f32x4 oacc[4];
#pragma unroll
    for (int i = 0; i < 4; i++) oacc[i] = (f32x4){0.f, 0.f, 0.f, 0.f};
    float lsum = 0.f;

    gld_lds16(gK0, &Ks[0][0][wave * 16][0]);
    gld_lds16(gK1, &Ks[0][1][wave * 16][0]);
    gld_lds16(gV0, &Vs[0][0][wave * 16][0]);
    gld_lds16(gV1, &Vs[0][1][wave * 16][0]);
    PHASE_BAR();

    int buf = 0;
    for (int kv0 = 0; kv0 < SEQ; kv0 += 64) {
        if (kv0 + 64 < SEQ) {
            size_t koff = (size_t)(kv0 + 64) * QKVN;
            gld_lds16(gK0 + koff, &Ks[buf ^ 1][0][wave * 16][0]);
            gld_lds16(gK1 + koff, &Ks[buf ^ 1][1][wave * 16][0]);
            gld_lds16(gV0 + kv0 + 64, &Vs[buf ^ 1][0][wave * 16][0]);
            gld_lds16(gV1 + kv0 + 64, &Vs[buf ^ 1][1][wave * 16][0]);
        }

        f32x4 s[4];
#pragma unroll
        for (int t = 0; t < 4; t++) {
            bf16x8 af0 = *(const bf16x8*)(&Ks[buf][0][t * 16 + l16][quad * 8]);
            bf16x8 af1 = *(const bf16x8*)(&Ks[buf][1][t * 16 + l16][quad * 8]);
            f32x4 z = (f32x4){0.f, 0.f, 0.f, 0.f};
            z = __builtin_amdgcn_mfma_f32_16x16x32_bf16(af0, qf[0], z, 0, 0, 0);
            z = __builtin_amdgcn_mfma_f32_16x16x32_bf16(af1, qf[1], z, 0, 0, 0);
            s[t] = z;
        }

        bf16x4 p[4];
#pragma unroll
        for (int t = 0; t < 4; t++)
#pragma unroll
            for (int r = 0; r < 4; r++) {
                float pf = fast_exp2(s[t][r]);
                lsum += pf;
                p[t][r] = (bf16)pf;
            }

#pragma unroll
        for (int tp = 0; tp < 2; tp++) {
            bf16x8 pa = __builtin_shufflevector(p[2 * tp], p[2 * tp + 1], 0, 1, 2, 3, 4, 5, 6, 7);
#pragma unroll
            for (int nt = 0; nt < 4; nt++) {
                bf16x8 vb = *(const bf16x8*)(&Vs[buf][tp][nt * 16 + l16][quad * 8]);
                oacc[nt] = __builtin_amdgcn_mfma_f32_16x16x32_bf16(pa, vb, oacc[nt], 0, 0, 0);
            }
        }

        PHASE_BAR();
        buf ^= 1;
    }

    lsum += __shfl_xor(lsum, 16, 64);
    lsum += __shfl_xor(lsum, 32, 64);
    float invl[4];
#pragma unroll
    for (int r = 0; r < 4; r++)
        invl[r] = 1.0f / __shfl(lsum, quad * 4 + r, 16);

#pragma unroll
    for (int nt = 0; nt < 4; nt++)
#pragma unroll
        for (int r = 0; r < 4; r++)
            o[(size_t)(b * SEQ + q0 + quad * 4 + r) * D_MODEL + h * HDIM + nt * 16 + l16] =
                (bf16)(oacc[nt][r] * invl[r]);
}

// ---------------- launcher ----------------
extern "C" void kernel_launch(void* const* d_in, const int* in_sizes, int n_in,
                              void* d_out, int out_size, void* d_ws, size_t ws_size,
                              hipStream_t stream) {
    const float* x     = (const float*)d_in[0];
    const float* ln1_g = (const float*)d_in[1];
    const float* ln1_b = (const float*)d_in[2];
    const float* w_qkv = (const float*)d_in[3];
    const float* b_qkv = (const float*)d_in[4];
    const float* w_out = (const float*)d_in[5];
    const float* b_out = (const float*)d_in[6];
    const float* ln2_g = (const float*)d_in[7];
    const float* ln2_b = (const float*)d_in[8];
    const float* w_fc1 = (const float*)d_in[9];
    const float* b_fc1 = (const float*)d_in[10];
    const float* w_fc2 = (const float*)d_in[11];
    const float* b_fc2 = (const float*)d_in[12];
    float* out = (float*)d_out;

    uintptr_t ws = (uintptr_t)d_ws;
    bf16* wt_qkv = (bf16*)(ws + 0);                  //  6291456 B
    bf16* wt_out = (bf16*)(ws + 6291456);            //  2097152 B
    bf16* wt_fc1 = (bf16*)(ws + 8388608);            //  8388608 B
    bf16* wt_fc2 = (bf16*)(ws + 16777216);           //  8388608 B
    bf16* hbuf   = (bf16*)(ws + 25165824);           //  8388608 B
    bf16* vT     = hbuf;
    bf16* qkv    = (bf16*)(ws + 33554432);           // 25165824 B
    bf16* attn_o = (bf16*)(ws + 58720256);           //  8388608 B
    bf16* hgelu  = (bf16*)(ws + 33554432);           // 33554432 B (overlays dead qkv+attn_o)

    k_transpose_all<<<12288, dim3(32, 8), 0, stream>>>(w_qkv, w_out, w_fc1, w_fc2,
                                                       wt_qkv, wt_out, wt_fc1, wt_fc2);

    k_layernorm<<<NTOK, 256, 0, stream>>>(x, ln1_g, ln1_b, hbuf);

    // QKV: 256^2 fine-phase depth-3 kernel, grid 12x16 = 192 blocks
    k_gemm256<0><<<dim3(QKVN / 256, NTOK / 256), 512, 0, stream>>>(
        hbuf, wt_qkv, b_qkv, qkv, NTOK, QKVN, D_MODEL);

    k_vtrans<<<dim3(NTOK / 32, D_MODEL / 32), dim3(32, 8), 0, stream>>>(qkv, vT);

    k_attention2<<<dim3(SEQ / 64, BATCH * NHEAD), 256, 0, stream>>>(qkv, vT, attn_o);

    // out-proj: BN=64, reg-staged 2-deep pipeline
    k_gemm<0, 1, 0, 64><<<dim3(D_MODEL / 64, NTOK / 128), 256, 0, stream>>>(
        attn_o, wt_out, b_out, x, out, nullptr, NTOK, D_MODEL, D_MODEL);

    k_layernorm<<<NTOK, 256, 0, stream>>>(out, ln2_g, ln2_b, hbuf);

    // FC1: 256^2 fine-phase depth-3 kernel + fast GELU, grid 16x16 = 256 blocks
    k_gemm256<1><<<dim3(FFDIM / 256, NTOK / 256), 512, 0, stream>>>(
        hbuf, wt_fc1, b_fc1, hgelu, NTOK, FFDIM, D_MODEL);

    // FC2: 128^2 fine-phase, split-K=2 (grid 8x32x2 = 512 blocks, 2/CU), fp32
    // atomicAdd into out (already holds out-proj+residual); z==0 adds bias.
    k_gemm128fp<2><<<dim3(D_MODEL / 128, NTOK / 128, 2), 256, 0, stream>>>(
        hgelu, wt_fc2, b_fc2, out, NTOK, D_MODEL, FFDIM);
}

// Round 10
// 344.788 us; speedup vs baseline: 1.0429x; 1.0054x over previous
//
#include <hip/hip_runtime.h>
#include <stdint.h>
#include <math.h>

#define D_MODEL 1024
#define NHEAD   16
#define HDIM    64
#define FFDIM   4096
#define SEQ     2048
#define BATCH   2
#define NTOK    (BATCH*SEQ)
#define QKVN    (3*D_MODEL)

typedef __bf16 bf16;
typedef __attribute__((ext_vector_type(8))) __bf16 bf16x8;
typedef __attribute__((ext_vector_type(4))) __bf16 bf16x4;
typedef __attribute__((ext_vector_type(4))) float f32x4;

__device__ __forceinline__ void gld_lds16(const void* g, void* l) {
    __builtin_amdgcn_global_load_lds((__attribute__((address_space(1))) void*)g,
                                     (__attribute__((address_space(3))) void*)l,
                                     16, 0, 0);
}

__device__ __forceinline__ float fast_exp2(float x) {
#if __has_builtin(__builtin_amdgcn_exp2f)
    return __builtin_amdgcn_exp2f(x);
#else
    return __expf(x * 0.69314718056f);
#endif
}

__device__ __forceinline__ float fast_rcp(float x) {
#if __has_builtin(__builtin_amdgcn_rcpf)
    return __builtin_amdgcn_rcpf(x);
#else
    return 1.0f / x;
#endif
}

// tanh-form GELU: max |err vs erf-gelu| ~3e-4, below bf16 output quantization.
__device__ __forceinline__ float gelu_fast(float x) {
    float xx = x * x;
    float y  = x * fmaf(0.035677408137f, xx, 0.7978845608f);
    float z  = fminf(-2.8853900817779268f * y, 126.0f);
    float e  = fast_exp2(z);
    return x * fast_rcp(1.0f + e);
}

#define BARRIER() do {                                         \
    __builtin_amdgcn_s_barrier();                              \
    asm volatile("" ::: "memory");                             \
} while (0)
#define LGKM0() asm volatile("s_waitcnt lgkmcnt(0)" ::: "memory")
#define VMW(N)  asm volatile("s_waitcnt vmcnt(" #N ")" ::: "memory")

// 2-phase boundary for the attention pipeline
#define PHASE_BAR() do {                                       \
    asm volatile("s_waitcnt vmcnt(0)" ::: "memory");           \
    __builtin_amdgcn_s_barrier();                              \
    asm volatile("" ::: "memory");                             \
} while (0)

// ---------------- all 4 weight transposes (fp32 W[K][N] -> bf16 Wt[N][K]) ----------------
__global__ __launch_bounds__(256)
void k_transpose_all(const float* __restrict__ w_qkv, const float* __restrict__ w_out,
                     const float* __restrict__ w_fc1, const float* __restrict__ w_fc2,
                     bf16* __restrict__ t_qkv, bf16* __restrict__ t_out,
                     bf16* __restrict__ t_fc1, bf16* __restrict__ t_fc2) {
    __shared__ float tile[32][33];
    int bid = blockIdx.x;
    const float* W; bf16* Wt; int K, N, ti;
    if (bid < 3072)       { W = w_qkv; Wt = t_qkv; K = 1024; N = 3072; ti = bid; }
    else if (bid < 4096)  { W = w_out; Wt = t_out; K = 1024; N = 1024; ti = bid - 3072; }
    else if (bid < 8192)  { W = w_fc1; Wt = t_fc1; K = 1024; N = 4096; ti = bid - 4096; }
    else                  { W = w_fc2; Wt = t_fc2; K = 4096; N = 1024; ti = bid - 8192; }
    int tn = N >> 5;
    int n0 = (ti % tn) * 32, k0 = (ti / tn) * 32;
    int tx = threadIdx.x, ty = threadIdx.y;
#pragma unroll
    for (int i = 0; i < 4; i++)
        tile[ty + i * 8][tx] = W[(size_t)(k0 + ty + i * 8) * N + n0 + tx];
    __syncthreads();
#pragma unroll
    for (int i = 0; i < 4; i++)
        Wt[(size_t)(n0 + ty + i * 8) * K + k0 + tx] = (bf16)tile[tx][ty + i * 8];
}

// ---------------- V transpose + MFMA-k-slot token permutation ----------------
__global__ __launch_bounds__(256)
void k_vtrans(const bf16* __restrict__ qkv, bf16* __restrict__ vT) {
    __shared__ bf16 t[32][33];
    int tok0 = blockIdx.x * 32, f0 = blockIdx.y * 32;
    int tx = threadIdx.x, ty = threadIdx.y;
#pragma unroll
    for (int i = 0; i < 4; i++)
        t[ty + i * 8][tx] = qkv[(size_t)(tok0 + ty + i * 8) * QKVN + 2 * D_MODEL + f0 + tx];
    __syncthreads();
    int s = tx;
    int pp = (s < 16) ? ((s >> 2) * 8 + (s & 3))
                      : (((s - 16) >> 2) * 8 + ((s - 16) & 3) + 4);
#pragma unroll
    for (int i = 0; i < 4; i++)
        vT[(size_t)(f0 + ty + i * 8) * NTOK + tok0 + pp] = t[tx][ty + i * 8];
}

// ---------------- LayerNorm (row = 1024 fp32) -> bf16 ----------------
__global__ __launch_bounds__(256)
void k_layernorm(const float* __restrict__ x, const float* __restrict__ g,
                 const float* __restrict__ b, bf16* __restrict__ out) {
    int row = blockIdx.x;
    int tid = threadIdx.x;
    float4 v = ((const float4*)(x + (size_t)row * D_MODEL))[tid];
    float s  = v.x + v.y + v.z + v.w;
    float ss = v.x * v.x + v.y * v.y + v.z * v.z + v.w * v.w;
#pragma unroll
    for (int off = 32; off > 0; off >>= 1) {
        s  += __shfl_down(s, off, 64);
        ss += __shfl_down(ss, off, 64);
    }
    __shared__ float red[2][4];
    __shared__ float mv[2];
    int wave = tid >> 6, lane = tid & 63;
    if (lane == 0) { red[0][wave] = s; red[1][wave] = ss; }
    __syncthreads();
    if (tid == 0) {
        float S  = red[0][0] + red[0][1] + red[0][2] + red[0][3];
        float SS = red[1][0] + red[1][1] + red[1][2] + red[1][3];
        float mu = S * (1.0f / D_MODEL);
        float var = SS * (1.0f / D_MODEL) - mu * mu;
        mv[0] = mu;
        mv[1] = rsqrtf(var + 1e-5f);
    }
    __syncthreads();
    float mu = mv[0], rs = mv[1];
    float4 gv = ((const float4*)g)[tid];
    float4 bv = ((const float4*)b)[tid];
    bf16x4 ov = { (bf16)((v.x - mu) * rs * gv.x + bv.x),
                  (bf16)((v.y - mu) * rs * gv.y + bv.y),
                  (bf16)((v.z - mu) * rs * gv.z + bv.z),
                  (bf16)((v.w - mu) * rs * gv.w + bv.w) };
    *(bf16x4*)(out + (size_t)row * D_MODEL + tid * 4) = ov;
}

// ---------------- 256x256 8-wave fine-phase MFMA GEMM, depth-3 pipeline (r8-proven) ----------------
template <int DO_GELU>
__global__ __launch_bounds__(512, 2)
void k_gemm256(const bf16* __restrict__ A, const bf16* __restrict__ Bt,
               const float* __restrict__ bias, bf16* __restrict__ outb,
               int M, int N, int K) {
    __shared__ bf16 LA[2][2][8192];   // [dbuf][khalf][256 rows x 32 elems]
    __shared__ bf16 LB[2][2][8192];

    int tid = threadIdx.x;
    int wid = tid >> 6, lane = tid & 63;
    int quad = lane >> 4, l16 = lane & 15;
    int wm = (wid >> 2) * 128;
    int wn = (wid & 3) * 64;

    int nwg = gridDim.x * gridDim.y;
    int bid = blockIdx.y * gridDim.x + blockIdx.x;
    int sid = (bid & 7) * (nwg >> 3) + (bid >> 3);
    int bx = sid % gridDim.x, by = sid / gridDim.x;
    int m0 = by * 256, n0 = bx * 256;

    int l = lane;
    int rsw = l >> 2;
    int csw = 8 * ((l & 3) ^ ((l >> 3) & 3));
    const bf16* pA = A  + (size_t)(m0 + 32 * wid + rsw) * K + csw;
    const bf16* pB = Bt + (size_t)(n0 + 32 * wid + rsw) * K + csw;
    int sbase = wid * 1024;

    int xq = 8 * (quad ^ ((l16 >> 1) & 3));

    f32x4 acc[8][4];
#pragma unroll
    for (int i = 0; i < 8; i++)
#pragma unroll
        for (int j = 0; j < 4; j++) acc[i][j] = (f32x4){0.f, 0.f, 0.f, 0.f};

#define STAGE_A(buf, kh, t) do {                                               \
    gld_lds16(pA + (size_t)(t) * 64 + (kh) * 32,              &LA[buf][kh][sbase]);       \
    gld_lds16(pA + (size_t)16 * K + (size_t)(t) * 64 + (kh) * 32, &LA[buf][kh][sbase + 512]); \
} while (0)
#define STAGE_B(buf, kh, t) do {                                               \
    gld_lds16(pB + (size_t)(t) * 64 + (kh) * 32,              &LB[buf][kh][sbase]);       \
    gld_lds16(pB + (size_t)16 * K + (size_t)(t) * 64 + (kh) * 32, &LB[buf][kh][sbase + 512]); \
} while (0)

    bf16x8 af[4], bfr[4];
#define RD_B(buf, kh)  do {                                                    \
    _Pragma("unroll")                                                          \
    for (int fc = 0; fc < 4; fc++)                                             \
        bfr[fc] = *(const bf16x8*)&LB[buf][kh][(wn + fc * 16 + l16) * 32 + xq];\
} while (0)
#define RD_A(buf, kh, rh) do {                                                 \
    _Pragma("unroll")                                                          \
    for (int fr = 0; fr < 4; fr++)                                             \
        af[fr] = *(const bf16x8*)&LA[buf][kh][(wm + (rh) * 64 + fr * 16 + l16) * 32 + xq]; \
} while (0)
#define MFMA16(rh) do {                                                        \
    __builtin_amdgcn_s_setprio(1);                                             \
    _Pragma("unroll")                                                          \
    for (int fr = 0; fr < 4; fr++)                                             \
        _Pragma("unroll")                                                      \
        for (int fc = 0; fc < 4; fc++)                                         \
            acc[(rh) * 4 + fr][fc] =                                           \
                __builtin_amdgcn_mfma_f32_16x16x32_bf16(af[fr], bfr[fc],       \
                                                        acc[(rh) * 4 + fr][fc], 0, 0, 0); \
    __builtin_amdgcn_s_setprio(0);                                             \
} while (0)

    int nt = K / 64;
    int buf = 0;
    STAGE_A(0, 0, 0); STAGE_B(0, 0, 0);
    STAGE_A(0, 1, 0); STAGE_B(0, 1, 0);
    STAGE_A(1, 0, 1); STAGE_B(1, 0, 1);
    VMW(8); BARRIER();

    for (int t = 0; t < nt - 1; t++) {
        int ts = (t + 2 < nt) ? (t + 2) : (nt - 1);
        RD_B(buf, 0); RD_A(buf, 0, 0);
        STAGE_A(buf ^ 1, 1, t + 1);
        BARRIER(); LGKM0();
        MFMA16(0);
        BARRIER();
        RD_A(buf, 0, 1);
        STAGE_B(buf ^ 1, 1, t + 1);
        BARRIER(); LGKM0();
        MFMA16(1);
        VMW(8); BARRIER();
        RD_B(buf, 1); RD_A(buf, 1, 0);
        STAGE_A(buf, 0, ts);
        BARRIER(); LGKM0();
        MFMA16(0);
        BARRIER();
        RD_A(buf, 1, 1);
        STAGE_B(buf, 0, ts);
        BARRIER(); LGKM0();
        MFMA16(1);
        VMW(8); BARRIER();
        buf ^= 1;
    }
    RD_B(buf, 0); RD_A(buf, 0, 0);
    BARRIER(); LGKM0();
    MFMA16(0);
    BARRIER();
    RD_A(buf, 0, 1);
    BARRIER(); LGKM0();
    MFMA16(1);
    VMW(4); BARRIER();
    RD_B(buf, 1); RD_A(buf, 1, 0);
    BARRIER(); LGKM0();
    MFMA16(0);
    BARRIER();
    RD_A(buf, 1, 1);
    LGKM0();
    MFMA16(1);
    VMW(0);

#undef STAGE_A
#undef STAGE_B
#undef RD_A
#undef RD_B
#undef MFMA16

#pragma unroll
    for (int fi = 0; fi < 8; fi++) {
        int row = m0 + wm + fi * 16 + quad * 4;
#pragma unroll
        for (int fc = 0; fc < 4; fc++) {
            int col = n0 + wn + fc * 16 + l16;
            float bb = bias[col];
#pragma unroll
            for (int r = 0; r < 4; r++) {
                float v = acc[fi][fc][r] + bb;
                if (DO_GELU) v = gelu_fast(v);
                outb[(size_t)(row + r) * N + col] = (bf16)v;
            }
        }
    }
}

// ---------------- 128x64 4-wave fine-phase MFMA GEMM, depth-3, plain fp32 epilogue ----------------
// C[M][N] = A[M][K] @ Bt[N][K]^T + bias + res, fp32 out (NO atomics, NO split-K).
// Grid (N/64, M/128). 256 thr = 4 waves (2M x 2N), per-wave 64x32 = acc[4][2].
// res may ALIAS outf (FC2: out += ...), so res/outf are NOT __restrict__.
// LDS = 2dbuf x 2kh x (A 8KB + B 4KB) = 48 KB -> up to 3 blocks/CU.
// Depth-3 ledger (3-load stage-groups: A:2 + B:1, FIFO per wave):
//   entry: 6 in flight = [S(t,kh1):3][S(t+1,kh0):3]
//   phase kh0: RD(kh0); STAGE S(t+1,kh1)->buf^1 (9) | bar lgkm0 MFMA8 VMW(6) bar -> S(t,kh1) landed
//   phase kh1: RD(kh1); STAGE S(t+2,kh0)->buf   (9) | bar lgkm0 MFMA8 VMW(6) bar -> S(t+1,kh0) landed
//     (WAR-safe: buf's kh0 readers finished before phase-kh0's closing barrier)
//   tail staging clamped to nt-1 (dummy in unread slot); tail: VMW(3) then VMW(0).
// Swizzle identical to k_gemm256 (proven bank-conflict-free).
__global__ __launch_bounds__(256, 3)
void k_gemm128x64(const bf16* __restrict__ A, const bf16* __restrict__ Bt,
                  const float* __restrict__ bias, const float* res,
                  float* outf, int M, int N, int K) {
    __shared__ bf16 LA[2][2][4096];   // [dbuf][kh][128 rows x 32 elems] = 8KB each
    __shared__ bf16 LB[2][2][2048];   // [dbuf][kh][ 64 rows x 32 elems] = 4KB each

    int tid = threadIdx.x;
    int wid = tid >> 6, lane = tid & 63;
    int quad = lane >> 4, l16 = lane & 15;
    int wm = (wid >> 1) * 64;
    int wn = (wid & 1) * 32;

    int nwg = gridDim.x * gridDim.y;
    int bid = blockIdx.y * gridDim.x + blockIdx.x;
    int sid = (bid & 7) * (nwg >> 3) + (bid >> 3);
    int bx = sid % gridDim.x, by = sid / gridDim.x;
    int m0 = by * 128, n0 = bx * 64;

    int l = lane;
    int rsw = l >> 2;
    int csw = 8 * ((l & 3) ^ ((l >> 3) & 3));
    const bf16* pA = A  + (size_t)(m0 + 32 * wid + rsw) * K + csw;
    const bf16* pB = Bt + (size_t)(n0 + 16 * wid + rsw) * K + csw;
    int sbaseA = wid * 1024;          // 4 waves x (2 chunks x 512)
    int sbaseB = wid * 512;           // 4 waves x 512

    int xq = 8 * (quad ^ ((l16 >> 1) & 3));

    f32x4 acc[4][2];
#pragma unroll
    for (int i = 0; i < 4; i++)
#pragma unroll
        for (int j = 0; j < 2; j++) acc[i][j] = (f32x4){0.f, 0.f, 0.f, 0.f};

#define STAGE_AB(buf, kh, t) do {                                              \
    gld_lds16(pA + (size_t)(t) * 64 + (kh) * 32,                  &LA[buf][kh][sbaseA]);       \
    gld_lds16(pA + (size_t)16 * K + (size_t)(t) * 64 + (kh) * 32, &LA[buf][kh][sbaseA + 512]); \
    gld_lds16(pB + (size_t)(t) * 64 + (kh) * 32,                  &LB[buf][kh][sbaseB]);       \
} while (0)

    bf16x8 af[4], bfr[2];
#define RD(buf, kh)  do {                                                      \
    _Pragma("unroll")                                                          \
    for (int fc = 0; fc < 2; fc++)                                             \
        bfr[fc] = *(const bf16x8*)&LB[buf][kh][(wn + fc * 16 + l16) * 32 + xq];\
    _Pragma("unroll")                                                          \
    for (int fr = 0; fr < 4; fr++)                                             \
        af[fr] = *(const bf16x8*)&LA[buf][kh][(wm + fr * 16 + l16) * 32 + xq]; \
} while (0)
#define MFMA8() do {                                                           \
    __builtin_amdgcn_s_setprio(1);                                             \
    _Pragma("unroll")                                                          \
    for (int fr = 0; fr < 4; fr++)                                             \
        _Pragma("unroll")                                                      \
        for (int fc = 0; fc < 2; fc++)                                         \
            acc[fr][fc] =                                                      \
                __builtin_amdgcn_mfma_f32_16x16x32_bf16(af[fr], bfr[fc],       \
                                                        acc[fr][fc], 0, 0, 0); \
    __builtin_amdgcn_s_setprio(0);                                             \
} while (0)

    int nt = K / 64;                  // FC2: 64; out-proj: 16
    int buf = 0;
    // prologue: S(0,kh0), S(0,kh1), S(1,kh0) -> 9 in flight
    STAGE_AB(0, 0, 0);
    STAGE_AB(0, 1, 0);
    STAGE_AB(1, 0, 1);
    VMW(6); BARRIER();                // S(0,kh0) landed; 6 in flight

    for (int t = 0; t < nt - 1; t++) {
        int ts = (t + 2 < nt) ? (t + 2) : (nt - 1);
        // phase kh0
        RD(buf, 0);
        STAGE_AB(buf ^ 1, 1, t + 1);  // S(t+1,kh1) -> 9
        BARRIER(); LGKM0();
        MFMA8();
        VMW(6); BARRIER();            // S(t,kh1) landed
        // phase kh1
        RD(buf, 1);
        STAGE_AB(buf, 0, ts);         // S(t+2,kh0) -> 9 (WAR-safe, see header)
        BARRIER(); LGKM0();
        MFMA8();
        VMW(6); BARRIER();            // S(t+1,kh0) landed
        buf ^= 1;
    }
    // tile nt-1: entry 6 = [S(last,kh1):3][dummy:3]
    RD(buf, 0);
    BARRIER(); LGKM0();
    MFMA8();
    VMW(3); BARRIER();                // S(last,kh1) landed (3 dummies remain)
    RD(buf, 1);
    LGKM0();
    MFMA8();
    VMW(0);                           // drain dummies before LDS teardown

#undef STAGE_AB
#undef RD
#undef MFMA8

#pragma unroll
    for (int fr = 0; fr < 4; fr++) {
        int row = m0 + wm + fr * 16 + quad * 4;
#pragma unroll
        for (int fc = 0; fc < 2; fc++) {
            int col = n0 + wn + fc * 16 + l16;
            float bb = bias[col];
#pragma unroll
            for (int r = 0; r < 4; r++) {
                size_t idx = (size_t)(row + r) * N + col;
                outf[idx] = res[idx] + acc[fr][fc][r] + bb;
            }
        }
    }
}

// ---------------- attention: transposed-S flash, fixed-max softmax, 2-phase K/V pipeline ----------------
__global__ __launch_bounds__(256)
void k_attention2(const bf16* __restrict__ qkv, const bf16* __restrict__ vT,
                  bf16* __restrict__ o) {
    __shared__ bf16 Ks[2][2][64][32];
    __shared__ bf16 Vs[2][2][64][32];

    int tid = threadIdx.x, wave = tid >> 6, lane = tid & 63;
    int quad = lane >> 4, l16 = lane & 15;
    int bh = blockIdx.y;
    int b = bh >> 4, h = bh & 15;
    int q0 = blockIdx.x * 64 + wave * 16;

    const bf16* Qb  = qkv + (size_t)b * SEQ * QKVN + h * HDIM;
    const bf16* Kb  = Qb + D_MODEL;
    const bf16* vTb = vT + (size_t)h * HDIM * NTOK + b * SEQ;

    const float QSCALE = 0.125f * 1.44269504089f;
    bf16x8 qf[2];
#pragma unroll
    for (int c = 0; c < 2; c++) {
        bf16x8 qraw = *(const bf16x8*)(Qb + (size_t)(q0 + l16) * QKVN + c * 32 + quad * 8);
#pragma unroll
        for (int i = 0; i < 8; i++) qf[c][i] = (bf16)((float)qraw[i] * QSCALE);
    }

    const bf16* gK0 = Kb + (size_t)(wave * 16 + (lane >> 2)) * QKVN + (lane & 3) * 8;
    const bf16* gK1 = gK0 + 32;
    const bf16* gV0 = vTb + (size_t)(wave * 16 + (lane >> 2)) * NTOK + (lane & 3) * 8;
    const bf16* gV1 = gV0 + 32;

    f32x4 oacc[4];
#pragma unroll
    for (int i = 0; i < 4; i++) oacc[i] = (f32x4){0.f, 0.f, 0.f, 0.f};
    float lsum = 0.f;

    gld_lds16(gK0, &Ks[0][0][wave * 16][0]);
    gld_lds16(gK1, &Ks[0][1][wave * 16][0]);
    gld_lds16(gV0, &Vs[0][0][wave * 16][0]);
    gld_lds16(gV1, &Vs[0][1][wave * 16][0]);
    PHASE_BAR();

    int buf = 0;
    for (int kv0 = 0; kv0 < SEQ; kv0 += 64) {
        if (kv0 + 64 < SEQ) {
            size_t koff = (size_t)(kv0 + 64) * QKVN;
            gld_lds16(gK0 + koff, &Ks[buf ^ 1][0][wave * 16][0]);
            gld_lds16(gK1 + koff, &Ks[buf ^ 1][1][wave * 16][0]);
            gld_lds16(gV0 + kv0 + 64, &Vs[buf ^ 1][0][wave * 16][0]);
            gld_lds16(gV1 + kv0 + 64, &Vs[buf ^ 1][1][wave * 16][0]);
        }

        f32x4 s[4];
#pragma unroll
        for (int t = 0; t < 4; t++) {
            bf16x8 af0 = *(const bf16x8*)(&Ks[buf][0][t * 16 + l16][quad * 8]);
            bf16x8 af1 = *(const bf16x8*)(&Ks[buf][1][t * 16 + l16][quad * 8]);
            f32x4 z = (f32x4){0.f, 0.f, 0.f, 0.f};
            z = __builtin_amdgcn_mfma_f32_16x16x32_bf16(af0, qf[0], z, 0, 0, 0);
            z = __builtin_amdgcn_mfma_f32_16x16x32_bf16(af1, qf[1], z, 0, 0, 0);
            s[t] = z;
        }

        bf16x4 p[4];
#pragma unroll
        for (int t = 0; t < 4; t++)
#pragma unroll
            for (int r = 0; r < 4; r++) {
                float pf = fast_exp2(s[t][r]);
                lsum += pf;
                p[t][r] = (bf16)pf;
            }

#pragma unroll
        for (int tp = 0; tp < 2; tp++) {
            bf16x8 pa = __builtin_shufflevector(p[2 * tp], p[2 * tp + 1], 0, 1, 2, 3, 4, 5, 6, 7);
#pragma unroll
            for (int nt = 0; nt < 4; nt++) {
                bf16x8 vb = *(const bf16x8*)(&Vs[buf][tp][nt * 16 + l16][quad * 8]);
                oacc[nt] = __builtin_amdgcn_mfma_f32_16x16x32_bf16(pa, vb, oacc[nt], 0, 0, 0);
            }
        }

        PHASE_BAR();
        buf ^= 1;
    }

    lsum += __shfl_xor(lsum, 16, 64);
    lsum += __shfl_xor(lsum, 32, 64);
    float invl[4];
#pragma unroll
    for (int r = 0; r < 4; r++)
        invl[r] = 1.0f / __shfl(lsum, quad * 4 + r, 16);

#pragma unroll
    for (int nt = 0; nt < 4; nt++)
#pragma unroll
        for (int r = 0; r < 4; r++)
            o[(size_t)(b * SEQ + q0 + quad * 4 + r) * D_MODEL + h * HDIM + nt * 16 + l16] =
                (bf16)(oacc[nt][r] * invl[r]);
}

// ---------------- launcher ----------------
extern "C" void kernel_launch(void* const* d_in, const int* in_sizes, int n_in,
                              void* d_out, int out_size, void* d_ws, size_t ws_size,
                              hipStream_t stream) {
    const float* x     = (const float*)d_in[0];
    const float* ln1_g = (const float*)d_in[1];
    const float* ln1_b = (const float*)d_in[2];
    const float* w_qkv = (const float*)d_in[3];
    const float* b_qkv = (const float*)d_in[4];
    const float* w_out = (const float*)d_in[5];
    const float* b_out = (const float*)d_in[6];
    const float* ln2_g = (const float*)d_in[7];
    const float* ln2_b = (const float*)d_in[8];
    const float* w_fc1 = (const float*)d_in[9];
    const float* b_fc1 = (const float*)d_in[10];
    const float* w_fc2 = (const float*)d_in[11];
    const float* b_fc2 = (const float*)d_in[12];
    float* out = (float*)d_out;

    uintptr_t ws = (uintptr_t)d_ws;
    bf16* wt_qkv = (bf16*)(ws + 0);                  //  6291456 B
    bf16* wt_out = (bf16*)(ws + 6291456);            //  2097152 B
    bf16* wt_fc1 = (bf16*)(ws + 8388608);            //  8388608 B
    bf16* wt_fc2 = (bf16*)(ws + 16777216);           //  8388608 B
    bf16* hbuf   = (bf16*)(ws + 25165824);           //  8388608 B
    bf16* vT     = hbuf;
    bf16* qkv    = (bf16*)(ws + 33554432);           // 25165824 B
    bf16* attn_o = (bf16*)(ws + 58720256);           //  8388608 B
    bf16* hgelu  = (bf16*)(ws + 33554432);           // 33554432 B (overlays dead qkv+attn_o)

    k_transpose_all<<<12288, dim3(32, 8), 0, stream>>>(w_qkv, w_out, w_fc1, w_fc2,
                                                       wt_qkv, wt_out, wt_fc1, wt_fc2);

    k_layernorm<<<NTOK, 256, 0, stream>>>(x, ln1_g, ln1_b, hbuf);

    // QKV: 256^2 fine-phase depth-3 kernel, grid 12x16 = 192 blocks
    k_gemm256<0><<<dim3(QKVN / 256, NTOK / 256), 512, 0, stream>>>(
        hbuf, wt_qkv, b_qkv, qkv, NTOK, QKVN, D_MODEL);

    k_vtrans<<<dim3(NTOK / 32, D_MODEL / 32), dim3(32, 8), 0, stream>>>(qkv, vT);

    k_attention2<<<dim3(SEQ / 64, BATCH * NHEAD), 256, 0, stream>>>(qkv, vT, attn_o);

    // out-proj: 128x64 fine-phase depth-3, grid 16x32 = 512 blocks; out = attn_o@W + b + x
    k_gemm128x64<<<dim3(D_MODEL / 64, NTOK / 128), 256, 0, stream>>>(
        attn_o, wt_out, b_out, x, out, NTOK, D_MODEL, D_MODEL);

    k_layernorm<<<NTOK, 256, 0, stream>>>(out, ln2_g, ln2_b, hbuf);

    // FC1: 256^2 fine-phase depth-3 kernel + fast GELU, grid 16x16 = 256 blocks
    k_gemm256<1><<<dim3(FFDIM / 256, NTOK / 256), 512, 0, stream>>>(
        hbuf, wt_fc1, b_fc1, hgelu, NTOK, FFDIM, D_MODEL);

    // FC2: 128x64 fine-phase depth-3, grid 16x32 = 512 blocks, K=4096 (nt=64);
    // out += hgelu@W + b (res aliases out; unique writes, no atomics, no split-K)
    k_gemm128x64<<<dim3(D_MODEL / 64, NTOK / 128), 256, 0, stream>>>(
        hgelu, wt_fc2, b_fc2, out, out, NTOK, D_MODEL, FFDIM);
}